// Round 5
// baseline (306.191 us; speedup 1.0000x reference)
//
#include <hip/hip_runtime.h>
#include <hip/hip_bf16.h>

#define T_SEQ 4096
#define NB 4
#define CEMB 2048
#define HS 128

typedef __attribute__((ext_vector_type(8))) short bf16x8;
typedef __attribute__((ext_vector_type(4))) float f32x4;

__device__ inline short f2bf(float f) {
    union { float f; unsigned u; } v; v.f = f;
    unsigned r = v.u + 0x7FFFu + ((v.u >> 16) & 1u);   // RNE
    return (short)(r >> 16);
}

__device__ inline void gld16(const void* gsrc, void* lds) {
    __builtin_amdgcn_global_load_lds(
        (const __attribute__((address_space(1))) unsigned*)gsrc,
        (__attribute__((address_space(3))) unsigned*)lds, 16, 0, 0);
}

// ---------------- kernel 1: W -> pre-swizzled bf16 LDS-image panels ----------
// Wt[mat][panel s][16KB panel], panel layout: byte = (n*128 + kk*2) ^ ((n&7)<<4)
// with n = output col (0..127), kk = k - s*64 (0..63). mat: 0=q,1=k,2=v.
__global__ __launch_bounds__(256) void wt_kernel(
    const float* __restrict__ Wq, const float* __restrict__ Wk,
    const float* __restrict__ Wv, short* __restrict__ Wt) {
    int d = blockIdx.x * 256 + threadIdx.x;     // 3*32*8192 = 786432
    int mat = d >> 18;                          // 262144 per matrix
    int rm  = d & 262143;
    int s   = rm >> 13;                         // panel 0..31
    int e   = rm & 8191;                        // element within panel
    int p   = e * 2;                            // stored byte offset
    int n   = p >> 7;                           // row preserved by swizzle
    int lin = p ^ ((n & 7) << 4);               // linear byte within panel
    int kk  = (lin & 127) >> 1;
    int k   = s * 64 + kk;
    const float* W = (mat == 0) ? Wq : (mat == 1) ? Wk : Wv;
    Wt[d] = f2bf(W[k * HS + n]);
}

// ---------------- kernel 2: q/k/v projection, 2-phase LDS pipeline -----------
// grid 768, XCD-chunked: wk = (bid&7)*96 + (bid>>3); mat = wk%3; mtile = wk/3.
// q (pre-scaled by C^-0.5), k: bf16 [B*T][128] ; v transposed: bf16 [B][128][T]
__global__ __launch_bounds__(256, 3) void proj_kernel(
    const float* __restrict__ x, const short* __restrict__ Wt,
    short* __restrict__ qg, short* __restrict__ kg, short* __restrict__ vtg) {
    __shared__ short Wlds[2][8192];   // 2 x 16KB panels

    const int tid = threadIdx.x;
    const int w   = tid >> 6;
    const int l   = tid & 63;
    const int lg  = l >> 4;     // 0..3
    const int lr  = l & 15;     // 0..15

    const int bid = blockIdx.x;
    const int wk  = (bid & 7) * 96 + (bid >> 3);   // same-XCD chunking
    const int mat = wk % 3;
    const int m0  = (wk / 3) * 64;

    const short* Wp = Wt + (long)mat * 262144;     // 32 panels of 8192 shorts

    f32x4 acc[8];
    #pragma unroll
    for (int b = 0; b < 8; b++) acc[b] = (f32x4){0.f, 0.f, 0.f, 0.f};

    // x source: row m0 + w*16 + lr
    const float* xrow = x + (long)(m0 + w * 16 + lr) * CEMB;

    // per-lane swizzled LDS byte offsets for the 16 B-fragments
    const int sw = (lr & 7) << 4;

    // ---- prologue: stage panel 0, preload x k-step 0 ----
    {
        const short* gp = Wp + (long)(w * 4) * 512 + l * 8;
        #pragma unroll
        for (int j = 0; j < 4; j++)
            gld16(gp + j * 512, &Wlds[0][(w * 4 + j) * 512]);
    }
    float4 c0 = *reinterpret_cast<const float4*>(xrow + lg * 8);
    float4 c1 = *reinterpret_cast<const float4*>(xrow + lg * 8 + 4);
    float4 c2 = *reinterpret_cast<const float4*>(xrow + 32 + lg * 8);
    float4 c3 = *reinterpret_cast<const float4*>(xrow + 32 + lg * 8 + 4);
    __syncthreads();

    #pragma unroll 2
    for (int s = 0; s < 32; ++s) {
        const int cur = s & 1;

        // ---- stage next panel + prefetch next x ----
        float4 n0 = c0, n1 = c1, n2 = c2, n3 = c3;
        if (s < 31) {
            const short* gp = Wp + (long)(s + 1) * 8192 + (long)(w * 4) * 512 + l * 8;
            #pragma unroll
            for (int j = 0; j < 4; j++)
                gld16(gp + j * 512, &Wlds[cur ^ 1][(w * 4 + j) * 512]);
            const float* xn = xrow + (s + 1) * 64 + lg * 8;
            n0 = *reinterpret_cast<const float4*>(xn);
            n1 = *reinterpret_cast<const float4*>(xn + 4);
            n2 = *reinterpret_cast<const float4*>(xn + 32);
            n3 = *reinterpret_cast<const float4*>(xn + 36);
        }

        // ---- A fragments (ks = 0,1) ----
        bf16x8 a0, a1;
        a0[0] = f2bf(c0.x); a0[1] = f2bf(c0.y); a0[2] = f2bf(c0.z); a0[3] = f2bf(c0.w);
        a0[4] = f2bf(c1.x); a0[5] = f2bf(c1.y); a0[6] = f2bf(c1.z); a0[7] = f2bf(c1.w);
        a1[0] = f2bf(c2.x); a1[1] = f2bf(c2.y); a1[2] = f2bf(c2.z); a1[3] = f2bf(c2.w);
        a1[4] = f2bf(c3.x); a1[5] = f2bf(c3.y); a1[6] = f2bf(c3.z); a1[7] = f2bf(c3.w);

        // ---- B fragments from LDS (swizzled) + MFMA ----
        const char* lbase = (const char*)&Wlds[cur][0];
        #pragma unroll
        for (int ks = 0; ks < 2; ks++) {
            const bf16x8 afr = ks ? a1 : a0;
            #pragma unroll
            for (int nt = 0; nt < 8; nt++) {
                int off = (((nt * 16 + lr) * 128 + lg * 16 + ks * 64)) ^ sw;
                bf16x8 bfr = *reinterpret_cast<const bf16x8*>(lbase + off);
                acc[nt] = __builtin_amdgcn_mfma_f32_16x16x32_bf16(
                    afr, bfr, acc[nt], 0, 0, 0);
            }
        }

        __syncthreads();   // vmcnt(0)+lgkmcnt(0)+barrier: next panel ready
        c0 = n0; c1 = n1; c2 = n2; c3 = n3;
    }

    // ---- store (D layout: col=l&15, row=(l>>4)*4+reg) ----
    if (mat == 0) {
        const float scale = 0.022097086912079612f;  // 2048^-0.5 folded into q
        #pragma unroll
        for (int nt = 0; nt < 8; nt++)
            #pragma unroll
            for (int r = 0; r < 4; r++) {
                int row = m0 + w * 16 + lg * 4 + r;
                qg[(long)row * HS + nt * 16 + lr] = f2bf(acc[nt][r] * scale);
            }
    } else if (mat == 1) {
        #pragma unroll
        for (int nt = 0; nt < 8; nt++)
            #pragma unroll
            for (int r = 0; r < 4; r++) {
                int row = m0 + w * 16 + lg * 4 + r;
                kg[(long)row * HS + nt * 16 + lr] = f2bf(acc[nt][r]);
            }
    } else {
        #pragma unroll
        for (int nt = 0; nt < 8; nt++)
            #pragma unroll
            for (int r = 0; r < 4; r++) {
                int row = m0 + w * 16 + lg * 4 + r;
                int b   = row >> 12;
                int tl  = row & 4095;
                vtg[(long)b * (HS * T_SEQ) + (long)(nt * 16 + lr) * T_SEQ + tl]
                    = f2bf(acc[nt][r]);
            }
    }
}

// ---------------- kernel 3: causal flash attention, 1 wave/block -------------
// grid 1024: xcd = bid&7 pins batch b = xcd>>1 to one XCD (K/V 2MB fits 4MB L2);
// qt descends with bid (longest-first). All K/V fragments read direct from
// global (L2-resident); no __syncthreads anywhere.
__global__ __launch_bounds__(64) void attn_kernel(
    const short* __restrict__ qg, const short* __restrict__ kg,
    const short* __restrict__ vtg, float* __restrict__ out) {
    __shared__ short P_lds[16][72];   // per-wave P transpose buffer

    const int l   = threadIdx.x;  // 0..63
    const int lg  = l >> 4;
    const int lr  = l & 15;

    const int bid = blockIdx.x;
    const int xcd = bid & 7;
    const int idx = bid >> 3;                       // 0..127
    const int b   = xcd >> 1;                       // batch pinned to XCD pair
    const int qt  = 255 - ((idx << 1) | (xcd & 1)); // 0..255, descending
    const int q0  = qt * 16;

    const short* kb = kg  + (long)b * T_SEQ * HS;
    const short* vb = vtg + (long)b * HS * T_SEQ;

    // Q fragments (A: row=lr, k=lg*8+j), q pre-scaled by C^-0.5
    bf16x8 qf[4];
    #pragma unroll
    for (int ks = 0; ks < 4; ks++)
        qf[ks] = *reinterpret_cast<const bf16x8*>(
            &qg[((long)(b * T_SEQ + q0 + lr)) * HS + ks * 32 + lg * 8]);

    f32x4 acc[8];
    #pragma unroll
    for (int nt = 0; nt < 8; nt++) acc[nt] = (f32x4){0.f, 0.f, 0.f, 0.f};
    float mrow[4] = {-__builtin_inff(), -__builtin_inff(), -__builtin_inff(), -__builtin_inff()};
    float lsum[4] = {0.f, 0.f, 0.f, 0.f};

    const int ntk = (q0 + 15) / 64 + 1;

    for (int it = 0; it < ntk; ++it) {
        const int kv0 = it * 64;

        // ---- S = Q @ K^T (16 x 64), K fragments direct from global ----
        f32x4 s[4];
        #pragma unroll
        for (int nt = 0; nt < 4; nt++) {
            s[nt] = (f32x4){0.f, 0.f, 0.f, 0.f};
            #pragma unroll
            for (int ks = 0; ks < 4; ks++) {
                bf16x8 kf = *reinterpret_cast<const bf16x8*>(
                    &kb[(long)(kv0 + nt * 16 + lr) * HS + ks * 32 + lg * 8]);
                s[nt] = __builtin_amdgcn_mfma_f32_16x16x32_bf16(qf[ks], kf, s[nt], 0, 0, 0);
            }
        }

        // ---- mask (boundary tile only) ----
        float pv[4][4];
        if (kv0 + 63 <= q0) {       // fully valid tile, no mask
            #pragma unroll
            for (int nt = 0; nt < 4; nt++)
                #pragma unroll
                for (int r = 0; r < 4; r++) pv[nt][r] = s[nt][r];
        } else {
            #pragma unroll
            for (int nt = 0; nt < 4; nt++)
                #pragma unroll
                for (int r = 0; r < 4; r++) {
                    int qi = q0 + lg * 4 + r;
                    int kj = kv0 + nt * 16 + lr;
                    pv[nt][r] = (kj > qi) ? -__builtin_inff() : s[nt][r];
                }
        }

        // ---- online softmax (row = lg*4+r; reduce over lr via 16-lane shfl) ----
        float mnew[4], fac[4];
        #pragma unroll
        for (int r = 0; r < 4; r++) {
            float t = fmaxf(fmaxf(pv[0][r], pv[1][r]), fmaxf(pv[2][r], pv[3][r]));
            t = fmaxf(t, __shfl_xor(t, 1));
            t = fmaxf(t, __shfl_xor(t, 2));
            t = fmaxf(t, __shfl_xor(t, 4));
            t = fmaxf(t, __shfl_xor(t, 8));
            mnew[r] = fmaxf(mrow[r], t);
            fac[r]  = __expf(mrow[r] - mnew[r]);   // first tile: exp(-inf)=0
        }
        #pragma unroll
        for (int nt = 0; nt < 4; nt++)
            #pragma unroll
            for (int r = 0; r < 4; r++)
                pv[nt][r] = __expf(pv[nt][r] - mnew[r]);   // masked -> 0
        #pragma unroll
        for (int r = 0; r < 4; r++) {
            float t = pv[0][r] + pv[1][r] + pv[2][r] + pv[3][r];
            t += __shfl_xor(t, 1);
            t += __shfl_xor(t, 2);
            t += __shfl_xor(t, 4);
            t += __shfl_xor(t, 8);
            lsum[r] = lsum[r] * fac[r] + t;
            mrow[r] = mnew[r];
        }
        #pragma unroll
        for (int nt = 0; nt < 8; nt++)
            #pragma unroll
            for (int r = 0; r < 4; r++) acc[nt][r] *= fac[r];

        // ---- P -> LDS transpose (wave-internal, no barrier needed) ----
        #pragma unroll
        for (int nt = 0; nt < 4; nt++)
            #pragma unroll
            for (int r = 0; r < 4; r++)
                P_lds[lg * 4 + r][nt * 16 + lr] = f2bf(pv[nt][r]);

        // ---- O += P @ V, V fragments direct from global (vtg [b][d][t]) ----
        #pragma unroll
        for (int ks = 0; ks < 2; ks++) {
            bf16x8 pa = *reinterpret_cast<const bf16x8*>(&P_lds[lr][ks * 32 + lg * 8]);
            #pragma unroll
            for (int nt = 0; nt < 8; nt++) {
                bf16x8 vf = *reinterpret_cast<const bf16x8*>(
                    &vb[(long)(nt * 16 + lr) * T_SEQ + kv0 + ks * 32 + lg * 8]);
                acc[nt] = __builtin_amdgcn_mfma_f32_16x16x32_bf16(pa, vf, acc[nt], 0, 0, 0);
            }
        }
    }

    // ---- epilogue: O / l ----
    #pragma unroll
    for (int nt = 0; nt < 8; nt++)
        #pragma unroll
        for (int r = 0; r < 4; r++) {
            int row = q0 + lg * 4 + r;
            out[((long)b * T_SEQ + row) * HS + nt * 16 + lr] = acc[nt][r] / lsum[r];
        }
}

// ---------------- launch ------------------------------------------------------
extern "C" void kernel_launch(void* const* d_in, const int* in_sizes, int n_in,
                              void* d_out, int out_size, void* d_ws, size_t ws_size,
                              hipStream_t stream) {
    const float* x  = (const float*)d_in[0];
    const float* Wk = (const float*)d_in[1];
    const float* Wq = (const float*)d_in[2];
    const float* Wv = (const float*)d_in[3];
    float* out = (float*)d_out;

    char* ws = (char*)d_ws;
    short* Wt  = (short*)ws;                                  // 1.5 MB (swizzled panels)
    short* qg  = (short*)(ws + 1572864);                      // 4 MB
    short* kg  = (short*)(ws + 1572864 + 4194304);            // 4 MB
    short* vtg = (short*)(ws + 1572864 + 8388608);            // 4 MB

    wt_kernel  <<<3072, 256, 0, stream>>>(Wq, Wk, Wv, Wt);
    proj_kernel<<<768,  256, 0, stream>>>(x, Wt, qg, kg, vtg);
    attn_kernel<<<1024, 64,  0, stream>>>(qg, kg, vtg, out);
}

// Round 6
// 238.185 us; speedup vs baseline: 1.2855x; 1.2855x over previous
//
#include <hip/hip_runtime.h>
#include <hip/hip_bf16.h>

#define T_SEQ 4096
#define NB 4
#define CEMB 2048
#define HS 128

typedef __attribute__((ext_vector_type(8))) short bf16x8;
typedef __attribute__((ext_vector_type(4))) float f32x4;

__device__ inline short f2bf(float f) {
    union { float f; unsigned u; } v; v.f = f;
    unsigned r = v.u + 0x7FFFu + ((v.u >> 16) & 1u);   // RNE
    return (short)(r >> 16);
}

__device__ inline void gld16(const void* gsrc, void* lds) {
    __builtin_amdgcn_global_load_lds(
        (const __attribute__((address_space(1))) unsigned*)gsrc,
        (__attribute__((address_space(3))) unsigned*)lds, 16, 0, 0);
}

// ---------------- kernel 1: W -> pre-swizzled bf16 LDS-image panels ----------
// Wt[mat][panel s][16KB panel], panel layout: byte = (n*128 + kk*2) ^ ((n&7)<<4)
// with n = output col (0..127), kk = k - s*64 (0..63). mat: 0=q,1=k,2=v.
__global__ __launch_bounds__(256) void wt_kernel(
    const float* __restrict__ Wq, const float* __restrict__ Wk,
    const float* __restrict__ Wv, short* __restrict__ Wt) {
    int d = blockIdx.x * 256 + threadIdx.x;     // 3*32*8192 = 786432
    int mat = d >> 18;                          // 262144 per matrix
    int rm  = d & 262143;
    int s   = rm >> 13;                         // panel 0..31
    int e   = rm & 8191;                        // element within panel
    int p   = e * 2;                            // stored byte offset
    int n   = p >> 7;                           // row preserved by swizzle
    int lin = p ^ ((n & 7) << 4);               // linear byte within panel
    int kk  = (lin & 127) >> 1;
    int k   = s * 64 + kk;
    const float* W = (mat == 0) ? Wq : (mat == 1) ? Wk : Wv;
    Wt[d] = f2bf(W[k * HS + n]);
}

// ---------------- kernel 2: q/k/v projection, 2-phase LDS pipeline -----------
// grid 768, XCD-chunked: wk = (bid&7)*96 + (bid>>3); mat = wk%3; mtile = wk/3.
// q (pre-scaled by C^-0.5), k: bf16 [B*T][128] ; v transposed: bf16 [B][128][T]
__global__ __launch_bounds__(256, 3) void proj_kernel(
    const float* __restrict__ x, const short* __restrict__ Wt,
    short* __restrict__ qg, short* __restrict__ kg, short* __restrict__ vtg) {
    __shared__ short Wlds[2][8192];   // 2 x 16KB panels

    const int tid = threadIdx.x;
    const int w   = tid >> 6;
    const int l   = tid & 63;
    const int lg  = l >> 4;     // 0..3
    const int lr  = l & 15;     // 0..15

    const int bid = blockIdx.x;
    const int wk  = (bid & 7) * 96 + (bid >> 3);   // same-XCD chunking
    const int mat = wk % 3;
    const int m0  = (wk / 3) * 64;

    const short* Wp = Wt + (long)mat * 262144;     // 32 panels of 8192 shorts

    f32x4 acc[8];
    #pragma unroll
    for (int b = 0; b < 8; b++) acc[b] = (f32x4){0.f, 0.f, 0.f, 0.f};

    const float* xrow = x + (long)(m0 + w * 16 + lr) * CEMB;
    const int sw = (lr & 7) << 4;

    {
        const short* gp = Wp + (long)(w * 4) * 512 + l * 8;
        #pragma unroll
        for (int j = 0; j < 4; j++)
            gld16(gp + j * 512, &Wlds[0][(w * 4 + j) * 512]);
    }
    float4 c0 = *reinterpret_cast<const float4*>(xrow + lg * 8);
    float4 c1 = *reinterpret_cast<const float4*>(xrow + lg * 8 + 4);
    float4 c2 = *reinterpret_cast<const float4*>(xrow + 32 + lg * 8);
    float4 c3 = *reinterpret_cast<const float4*>(xrow + 32 + lg * 8 + 4);
    __syncthreads();

    #pragma unroll 2
    for (int s = 0; s < 32; ++s) {
        const int cur = s & 1;

        float4 n0 = c0, n1 = c1, n2 = c2, n3 = c3;
        if (s < 31) {
            const short* gp = Wp + (long)(s + 1) * 8192 + (long)(w * 4) * 512 + l * 8;
            #pragma unroll
            for (int j = 0; j < 4; j++)
                gld16(gp + j * 512, &Wlds[cur ^ 1][(w * 4 + j) * 512]);
            const float* xn = xrow + (s + 1) * 64 + lg * 8;
            n0 = *reinterpret_cast<const float4*>(xn);
            n1 = *reinterpret_cast<const float4*>(xn + 4);
            n2 = *reinterpret_cast<const float4*>(xn + 32);
            n3 = *reinterpret_cast<const float4*>(xn + 36);
        }

        bf16x8 a0, a1;
        a0[0] = f2bf(c0.x); a0[1] = f2bf(c0.y); a0[2] = f2bf(c0.z); a0[3] = f2bf(c0.w);
        a0[4] = f2bf(c1.x); a0[5] = f2bf(c1.y); a0[6] = f2bf(c1.z); a0[7] = f2bf(c1.w);
        a1[0] = f2bf(c2.x); a1[1] = f2bf(c2.y); a1[2] = f2bf(c2.z); a1[3] = f2bf(c2.w);
        a1[4] = f2bf(c3.x); a1[5] = f2bf(c3.y); a1[6] = f2bf(c3.z); a1[7] = f2bf(c3.w);

        const char* lbase = (const char*)&Wlds[cur][0];
        #pragma unroll
        for (int ks = 0; ks < 2; ks++) {
            const bf16x8 afr = ks ? a1 : a0;
            #pragma unroll
            for (int nt = 0; nt < 8; nt++) {
                int off = (((nt * 16 + lr) * 128 + lg * 16 + ks * 64)) ^ sw;
                bf16x8 bfr = *reinterpret_cast<const bf16x8*>(lbase + off);
                acc[nt] = __builtin_amdgcn_mfma_f32_16x16x32_bf16(
                    afr, bfr, acc[nt], 0, 0, 0);
            }
        }

        __syncthreads();
        c0 = n0; c1 = n1; c2 = n2; c3 = n3;
    }

    if (mat == 0) {
        const float scale = 0.022097086912079612f;  // 2048^-0.5 folded into q
        #pragma unroll
        for (int nt = 0; nt < 8; nt++)
            #pragma unroll
            for (int r = 0; r < 4; r++) {
                int row = m0 + w * 16 + lg * 4 + r;
                qg[(long)row * HS + nt * 16 + lr] = f2bf(acc[nt][r] * scale);
            }
    } else if (mat == 1) {
        #pragma unroll
        for (int nt = 0; nt < 8; nt++)
            #pragma unroll
            for (int r = 0; r < 4; r++) {
                int row = m0 + w * 16 + lg * 4 + r;
                kg[(long)row * HS + nt * 16 + lr] = f2bf(acc[nt][r]);
            }
    } else {
        #pragma unroll
        for (int nt = 0; nt < 8; nt++)
            #pragma unroll
            for (int r = 0; r < 4; r++) {
                int row = m0 + w * 16 + lg * 4 + r;
                int b   = row >> 12;
                int tl  = row & 4095;
                vtg[(long)b * (HS * T_SEQ) + (long)(nt * 16 + lr) * T_SEQ + tl]
                    = f2bf(acc[nt][r]);
            }
    }
}

// ---------------- kernel 3: flash attention, KV-split 4 waves/block ----------
// grid 1024 x 256 threads. Block = one 16-row q-tile; wave w handles kv tiles
// w, w+4, w+8, ... with private online softmax; LDS merge at the end.
// K/V fragments direct from global (L2-resident, batch pinned to XCD pair).
__global__ __launch_bounds__(256, 4) void attn_kernel(
    const short* __restrict__ qg, const short* __restrict__ kg,
    const short* __restrict__ vtg, float* __restrict__ out) {
    __shared__ __align__(16) float Lacc[4][16][132];  // merge buf; also aliases P
    __shared__ float Lm[4][16], Ll[4][16];

    const int tid = threadIdx.x;
    const int w   = tid >> 6;     // wave 0..3 (kv-split index)
    const int l   = tid & 63;
    const int lg  = l >> 4;
    const int lr  = l & 15;

    const int bid = blockIdx.x;
    const int xcd = bid & 7;
    const int idx = bid >> 3;                       // 0..127
    const int b   = xcd >> 1;                       // batch pinned to XCD pair
    const int qt  = 255 - ((idx << 1) | (xcd & 1)); // 0..255, descending
    const int q0  = qt * 16;

    const short* kb = kg  + (long)b * T_SEQ * HS;
    const short* vb = vtg + (long)b * HS * T_SEQ;

    // wave-private P transpose buffer aliased into this wave's merge region
    short* Pw = (short*)&Lacc[w][0][0];             // layout [16][72] shorts

    // Q fragments (A: row=lr, k=lg*8+j), q pre-scaled by C^-0.5
    bf16x8 qf[4];
    #pragma unroll
    for (int ks = 0; ks < 4; ks++)
        qf[ks] = *reinterpret_cast<const bf16x8*>(
            &qg[((long)(b * T_SEQ + q0 + lr)) * HS + ks * 32 + lg * 8]);

    f32x4 acc[8];
    #pragma unroll
    for (int nt = 0; nt < 8; nt++) acc[nt] = (f32x4){0.f, 0.f, 0.f, 0.f};
    float mrow[4] = {-__builtin_inff(), -__builtin_inff(), -__builtin_inff(), -__builtin_inff()};
    float lsum[4] = {0.f, 0.f, 0.f, 0.f};

    const int ntk = (q0 + 15) / 64 + 1;

    for (int t = w; t < ntk; t += 4) {
        const int kv0 = t * 64;

        // ---- S = Q @ K^T (16 x 64), K fragments direct from global ----
        f32x4 s[4];
        #pragma unroll
        for (int nt = 0; nt < 4; nt++) {
            s[nt] = (f32x4){0.f, 0.f, 0.f, 0.f};
            #pragma unroll
            for (int ks = 0; ks < 4; ks++) {
                bf16x8 kf = *reinterpret_cast<const bf16x8*>(
                    &kb[(long)(kv0 + nt * 16 + lr) * HS + ks * 32 + lg * 8]);
                s[nt] = __builtin_amdgcn_mfma_f32_16x16x32_bf16(qf[ks], kf, s[nt], 0, 0, 0);
            }
        }

        // ---- mask (boundary tile only) ----
        float pv[4][4];
        if (kv0 + 63 <= q0) {
            #pragma unroll
            for (int nt = 0; nt < 4; nt++)
                #pragma unroll
                for (int r = 0; r < 4; r++) pv[nt][r] = s[nt][r];
        } else {
            #pragma unroll
            for (int nt = 0; nt < 4; nt++)
                #pragma unroll
                for (int r = 0; r < 4; r++) {
                    int qi = q0 + lg * 4 + r;
                    int kj = kv0 + nt * 16 + lr;
                    pv[nt][r] = (kj > qi) ? -__builtin_inff() : s[nt][r];
                }
        }

        // ---- online softmax (row = lg*4+r; reduce over lr via 16-lane shfl) ----
        float mnew[4], fac[4];
        #pragma unroll
        for (int r = 0; r < 4; r++) {
            float t2 = fmaxf(fmaxf(pv[0][r], pv[1][r]), fmaxf(pv[2][r], pv[3][r]));
            t2 = fmaxf(t2, __shfl_xor(t2, 1));
            t2 = fmaxf(t2, __shfl_xor(t2, 2));
            t2 = fmaxf(t2, __shfl_xor(t2, 4));
            t2 = fmaxf(t2, __shfl_xor(t2, 8));
            mnew[r] = fmaxf(mrow[r], t2);
            fac[r]  = __expf(mrow[r] - mnew[r]);
        }
        #pragma unroll
        for (int nt = 0; nt < 4; nt++)
            #pragma unroll
            for (int r = 0; r < 4; r++)
                pv[nt][r] = __expf(pv[nt][r] - mnew[r]);
        #pragma unroll
        for (int r = 0; r < 4; r++) {
            float t2 = pv[0][r] + pv[1][r] + pv[2][r] + pv[3][r];
            t2 += __shfl_xor(t2, 1);
            t2 += __shfl_xor(t2, 2);
            t2 += __shfl_xor(t2, 4);
            t2 += __shfl_xor(t2, 8);
            lsum[r] = lsum[r] * fac[r] + t2;
            mrow[r] = mnew[r];
        }
        #pragma unroll
        for (int nt = 0; nt < 8; nt++)
            #pragma unroll
            for (int r = 0; r < 4; r++) acc[nt][r] *= fac[r];

        // ---- P -> LDS transpose (wave-internal) ----
        #pragma unroll
        for (int nt = 0; nt < 4; nt++)
            #pragma unroll
            for (int r = 0; r < 4; r++)
                Pw[(lg * 4 + r) * 72 + nt * 16 + lr] = f2bf(pv[nt][r]);

        // ---- O += P @ V, V fragments direct from global (vtg [b][d][t]) ----
        #pragma unroll
        for (int ks = 0; ks < 2; ks++) {
            bf16x8 pa = *reinterpret_cast<const bf16x8*>(&Pw[lr * 72 + ks * 32 + lg * 8]);
            #pragma unroll
            for (int nt = 0; nt < 8; nt++) {
                bf16x8 vf = *reinterpret_cast<const bf16x8*>(
                    &vb[(long)(nt * 16 + lr) * T_SEQ + kv0 + ks * 32 + lg * 8]);
                acc[nt] = __builtin_amdgcn_mfma_f32_16x16x32_bf16(pa, vf, acc[nt], 0, 0, 0);
            }
        }
    }

    // ---- write wave partials to LDS ----
    __syncthreads();   // all waves done with their Pw aliases
    #pragma unroll
    for (int nt = 0; nt < 8; nt++)
        #pragma unroll
        for (int r = 0; r < 4; r++)
            Lacc[w][lg * 4 + r][nt * 16 + lr] = acc[nt][r];
    if (lr == 0) {
        #pragma unroll
        for (int r = 0; r < 4; r++) {
            Lm[w][lg * 4 + r] = mrow[r];
            Ll[w][lg * 4 + r] = lsum[r];
        }
    }
    __syncthreads();

    // ---- merge 4 partials: thread t -> row t>>4, cols (t&15)*8 .. +7 ----
    {
        const int row = tid >> 4;
        const int c0  = (tid & 15) * 8;
        float m0 = Lm[0][row], m1 = Lm[1][row], m2 = Lm[2][row], m3 = Lm[3][row];
        float ms = fmaxf(fmaxf(m0, m1), fmaxf(m2, m3));
        float f0 = __expf(m0 - ms), f1 = __expf(m1 - ms);
        float f2 = __expf(m2 - ms), f3 = __expf(m3 - ms);
        float L = Ll[0][row] * f0 + Ll[1][row] * f1 + Ll[2][row] * f2 + Ll[3][row] * f3;
        float inv = 1.0f / L;
        float* op = &out[((long)b * T_SEQ + q0 + row) * HS + c0];
        #pragma unroll
        for (int j = 0; j < 8; j++) {
            float o = Lacc[0][row][c0 + j] * f0 + Lacc[1][row][c0 + j] * f1
                    + Lacc[2][row][c0 + j] * f2 + Lacc[3][row][c0 + j] * f3;
            op[j] = o * inv;
        }
    }
}

// ---------------- launch ------------------------------------------------------
extern "C" void kernel_launch(void* const* d_in, const int* in_sizes, int n_in,
                              void* d_out, int out_size, void* d_ws, size_t ws_size,
                              hipStream_t stream) {
    const float* x  = (const float*)d_in[0];
    const float* Wk = (const float*)d_in[1];
    const float* Wq = (const float*)d_in[2];
    const float* Wv = (const float*)d_in[3];
    float* out = (float*)d_out;

    char* ws = (char*)d_ws;
    short* Wt  = (short*)ws;                                  // 1.5 MB (swizzled panels)
    short* qg  = (short*)(ws + 1572864);                      // 4 MB
    short* kg  = (short*)(ws + 1572864 + 4194304);            // 4 MB
    short* vtg = (short*)(ws + 1572864 + 8388608);            // 4 MB

    wt_kernel  <<<3072, 256, 0, stream>>>(Wq, Wk, Wv, Wt);
    proj_kernel<<<768,  256, 0, stream>>>(x, Wt, qg, kg, vtg);
    attn_kernel<<<1024, 256, 0, stream>>>(qg, kg, vtg, out);
}

// Round 7
// 165.039 us; speedup vs baseline: 1.8553x; 1.4432x over previous
//
#include <hip/hip_runtime.h>
#include <hip/hip_bf16.h>

#define T_SEQ 4096
#define NB 4
#define CEMB 2048
#define HS 128

typedef __attribute__((ext_vector_type(8))) short bf16x8;
typedef __attribute__((ext_vector_type(4))) float f32x4;
typedef __attribute__((ext_vector_type(16))) float f32x16;

__device__ inline short f2bf(float f) {
    union { float f; unsigned u; } v; v.f = f;
    unsigned r = v.u + 0x7FFFu + ((v.u >> 16) & 1u);   // RNE
    return (short)(r >> 16);
}

__device__ inline unsigned pk2(float lo, float hi) {
    return ((unsigned)(unsigned short)f2bf(lo)) | (((unsigned)(unsigned short)f2bf(hi)) << 16);
}

__device__ inline void gld16(const void* gsrc, void* lds) {
    __builtin_amdgcn_global_load_lds(
        (const __attribute__((address_space(1))) unsigned*)gsrc,
        (__attribute__((address_space(3))) unsigned*)lds, 16, 0, 0);
}

// ---------------- kernel 1: W -> pre-swizzled bf16 LDS-image panels ----------
__global__ __launch_bounds__(256) void wt_kernel(
    const float* __restrict__ Wq, const float* __restrict__ Wk,
    const float* __restrict__ Wv, short* __restrict__ Wt) {
    int d = blockIdx.x * 256 + threadIdx.x;     // 3*32*8192 = 786432
    int mat = d >> 18;
    int rm  = d & 262143;
    int s   = rm >> 13;                         // panel 0..31
    int e   = rm & 8191;
    int p   = e * 2;
    int n   = p >> 7;
    int lin = p ^ ((n & 7) << 4);
    int kk  = (lin & 127) >> 1;
    int k   = s * 64 + kk;
    const float* W = (mat == 0) ? Wq : (mat == 1) ? Wk : Wv;
    Wt[d] = f2bf(W[k * HS + n]);
}

// ---------------- kernel 2: q/k/v projection, 2-phase LDS pipeline -----------
// q pre-scaled by log2(e)/sqrt(2048); k: bf16 [B*T][128]; v: bf16 [B][128][T]
__global__ __launch_bounds__(256, 3) void proj_kernel(
    const float* __restrict__ x, const short* __restrict__ Wt,
    short* __restrict__ qg, short* __restrict__ kg, short* __restrict__ vtg) {
    __shared__ short Wlds[2][8192];   // 2 x 16KB panels

    const int tid = threadIdx.x;
    const int w   = tid >> 6;
    const int l   = tid & 63;
    const int lg  = l >> 4;
    const int lr  = l & 15;

    const int bid = blockIdx.x;
    const int wk  = (bid & 7) * 96 + (bid >> 3);   // same-XCD chunking
    const int mat = wk % 3;
    const int m0  = (wk / 3) * 64;

    const short* Wp = Wt + (long)mat * 262144;

    f32x4 acc[8];
    #pragma unroll
    for (int b = 0; b < 8; b++) acc[b] = (f32x4){0.f, 0.f, 0.f, 0.f};

    const float* xrow = x + (long)(m0 + w * 16 + lr) * CEMB;
    const int sw = (lr & 7) << 4;

    {
        const short* gp = Wp + (long)(w * 4) * 512 + l * 8;
        #pragma unroll
        for (int j = 0; j < 4; j++)
            gld16(gp + j * 512, &Wlds[0][(w * 4 + j) * 512]);
    }
    float4 c0 = *reinterpret_cast<const float4*>(xrow + lg * 8);
    float4 c1 = *reinterpret_cast<const float4*>(xrow + lg * 8 + 4);
    float4 c2 = *reinterpret_cast<const float4*>(xrow + 32 + lg * 8);
    float4 c3 = *reinterpret_cast<const float4*>(xrow + 32 + lg * 8 + 4);
    __syncthreads();

    #pragma unroll 2
    for (int s = 0; s < 32; ++s) {
        const int cur = s & 1;

        float4 n0 = c0, n1 = c1, n2 = c2, n3 = c3;
        if (s < 31) {
            const short* gp = Wp + (long)(s + 1) * 8192 + (long)(w * 4) * 512 + l * 8;
            #pragma unroll
            for (int j = 0; j < 4; j++)
                gld16(gp + j * 512, &Wlds[cur ^ 1][(w * 4 + j) * 512]);
            const float* xn = xrow + (s + 1) * 64 + lg * 8;
            n0 = *reinterpret_cast<const float4*>(xn);
            n1 = *reinterpret_cast<const float4*>(xn + 4);
            n2 = *reinterpret_cast<const float4*>(xn + 32);
            n3 = *reinterpret_cast<const float4*>(xn + 36);
        }

        bf16x8 a0, a1;
        a0[0] = f2bf(c0.x); a0[1] = f2bf(c0.y); a0[2] = f2bf(c0.z); a0[3] = f2bf(c0.w);
        a0[4] = f2bf(c1.x); a0[5] = f2bf(c1.y); a0[6] = f2bf(c1.z); a0[7] = f2bf(c1.w);
        a1[0] = f2bf(c2.x); a1[1] = f2bf(c2.y); a1[2] = f2bf(c2.z); a1[3] = f2bf(c2.w);
        a1[4] = f2bf(c3.x); a1[5] = f2bf(c3.y); a1[6] = f2bf(c3.z); a1[7] = f2bf(c3.w);

        const char* lbase = (const char*)&Wlds[cur][0];
        #pragma unroll
        for (int ks = 0; ks < 2; ks++) {
            const bf16x8 afr = ks ? a1 : a0;
            #pragma unroll
            for (int nt = 0; nt < 8; nt++) {
                int off = (((nt * 16 + lr) * 128 + lg * 16 + ks * 64)) ^ sw;
                bf16x8 bfr = *reinterpret_cast<const bf16x8*>(lbase + off);
                acc[nt] = __builtin_amdgcn_mfma_f32_16x16x32_bf16(
                    afr, bfr, acc[nt], 0, 0, 0);
            }
        }

        __syncthreads();
        c0 = n0; c1 = n1; c2 = n2; c3 = n3;
    }

    if (mat == 0) {
        const float scale = 0.0318793851f;  // log2(e) / sqrt(2048), folded into q
        #pragma unroll
        for (int nt = 0; nt < 8; nt++)
            #pragma unroll
            for (int r = 0; r < 4; r++) {
                int row = m0 + w * 16 + lg * 4 + r;
                qg[(long)row * HS + nt * 16 + lr] = f2bf(acc[nt][r] * scale);
            }
    } else if (mat == 1) {
        #pragma unroll
        for (int nt = 0; nt < 8; nt++)
            #pragma unroll
            for (int r = 0; r < 4; r++) {
                int row = m0 + w * 16 + lg * 4 + r;
                kg[(long)row * HS + nt * 16 + lr] = f2bf(acc[nt][r]);
            }
    } else {
        #pragma unroll
        for (int nt = 0; nt < 8; nt++)
            #pragma unroll
            for (int r = 0; r < 4; r++) {
                int row = m0 + w * 16 + lg * 4 + r;
                int b   = row >> 12;
                int tl  = row & 4095;
                vtg[(long)b * (HS * T_SEQ) + (long)(nt * 16 + lr) * T_SEQ + tl]
                    = f2bf(acc[nt][r]);
            }
    }
}

// ---------------- kernel 3: flash attention, swapped-QK 32x32, KV-split ------
// grid 512 x 256. Block = one 32-row q-tile, 4 waves, wave w does kv tiles
// w, w+4, ... (KVBLK=64). S^T = mfma32(K,Q): lane holds 32 kv-scores for ONE
// q-row (split with lane^32) -> in-lane softmax, 1 shfl per reduce. P->PV
// A-frags via pack + lane^32 exchange (no LDS). K/V direct from global.
__global__ __launch_bounds__(256, 2) void attn_kernel(
    const short* __restrict__ qg, const short* __restrict__ kg,
    const short* __restrict__ vtg, float* __restrict__ out) {
    __shared__ float Lacc[4][32][128];   // 64 KB merge buffer
    __shared__ float Lm[4][32];
    __shared__ float Ll[4][32];

    const int tid = threadIdx.x;
    const int w   = tid >> 6;      // wave = kv-split index
    const int l   = tid & 63;
    const int c31 = l & 31;
    const int hi  = l >> 5;
    const int hi4 = hi << 2;
    const int hi8 = hi << 3;

    const int bid = blockIdx.x;
    const int xcd = bid & 7;
    const int idx = bid >> 3;                        // 0..63
    const int b   = xcd >> 1;                        // batch pinned to XCD pair
    const int qt  = 127 - ((idx << 1) | (xcd & 1));  // 0..127, descending
    const int q0  = qt * 32;
    const int qrow = q0 + c31;                       // this lane's q-row

    const short* kb = kg  + (long)b * T_SEQ * HS;
    const short* vb = vtg + (long)b * HS * T_SEQ;

    // Q as B-operand: col = l&31 = q-row, k = kc*16 + hi*8 + j
    bf16x8 qf[8];
    #pragma unroll
    for (int kc = 0; kc < 8; kc++)
        qf[kc] = *reinterpret_cast<const bf16x8*>(
            &qg[(long)(b * T_SEQ + qrow) * HS + kc * 16 + hi8]);

    f32x16 accO[4];
    #pragma unroll
    for (int nb = 0; nb < 4; nb++)
        #pragma unroll
        for (int i = 0; i < 16; i++) accO[nb][i] = 0.f;
    float mrow = -__builtin_inff();
    float lsum = 0.f;

    const int ntk = (qt >> 1) + 1;

    #pragma unroll 1
    for (int t = w; t < ntk; t += 4) {
        const int kv0 = t * 64;

        // ---- S^T = K @ Q^T : two 32-kv blocks ----
        f32x16 SA, SB;
        #pragma unroll
        for (int i = 0; i < 16; i++) { SA[i] = 0.f; SB[i] = 0.f; }
        #pragma unroll
        for (int kc = 0; kc < 8; kc++) {
            bf16x8 ka = *reinterpret_cast<const bf16x8*>(
                &kb[(long)(kv0 + c31) * HS + kc * 16 + hi8]);
            bf16x8 kbf = *reinterpret_cast<const bf16x8*>(
                &kb[(long)(kv0 + 32 + c31) * HS + kc * 16 + hi8]);
            SA = __builtin_amdgcn_mfma_f32_32x32x16_bf16(ka,  qf[kc], SA, 0, 0, 0);
            SB = __builtin_amdgcn_mfma_f32_32x32x16_bf16(kbf, qf[kc], SB, 0, 0, 0);
        }

        // lane now holds scores for q-row (c31): kv_rel = (r&3)+8*(r>>2)+4*hi (+32 SB)
        float pA[16], pB[16];
        #pragma unroll
        for (int r = 0; r < 16; r++) { pA[r] = SA[r]; pB[r] = SB[r]; }

        // ---- causal mask (boundary tiles only) ----
        if (kv0 + 63 > q0) {
            #pragma unroll
            for (int r = 0; r < 16; r++) {
                int kr = kv0 + (r & 3) + 8 * (r >> 2) + hi4;
                pA[r] = (kr > qrow)      ? -__builtin_inff() : pA[r];
                pB[r] = (kr + 32 > qrow) ? -__builtin_inff() : pB[r];
            }
        }

        // ---- in-lane softmax (scores in log2 units; q pre-scaled) ----
        float t16[16];
        #pragma unroll
        for (int r = 0; r < 16; r++) t16[r] = fmaxf(pA[r], pB[r]);
        #pragma unroll
        for (int s2 = 8; s2 >= 1; s2 >>= 1)
            #pragma unroll
            for (int r = 0; r < 8; r++)
                if (r < s2) t16[r] = fmaxf(t16[r], t16[r + s2]);
        float mt   = fmaxf(t16[0], __shfl_xor(t16[0], 32));
        float mnew = fmaxf(mrow, mt);
        float fac  = exp2f(mrow - mnew);

        #pragma unroll
        for (int r = 0; r < 16; r++) {
            pA[r] = exp2f(pA[r] - mnew);
            pB[r] = exp2f(pB[r] - mnew);
        }
        float s16[16];
        #pragma unroll
        for (int r = 0; r < 16; r++) s16[r] = pA[r] + pB[r];
        #pragma unroll
        for (int s2 = 8; s2 >= 1; s2 >>= 1)
            #pragma unroll
            for (int r = 0; r < 8; r++)
                if (r < s2) s16[r] += s16[r + s2];
        float ts = s16[0] + __shfl_xor(s16[0], 32);
        lsum = lsum * fac + ts;
        mrow = mnew;

        #pragma unroll
        for (int nb = 0; nb < 4; nb++)
            #pragma unroll
            for (int i = 0; i < 16; i++) accO[nb][i] *= fac;

        // ---- pack P into PV A-frags: keep/send + lane^32 exchange ----
        // p-slot r holds kv_rel = 8*V + 4*hi + e where V = (r>>4)*4 + (r>>2)&3,
        // e = r&3. Frag kc needs kv = kc*16 + 8*hi_n + u.
        bf16x8 pf[4];
        #pragma unroll
        for (int kc = 0; kc < 4; kc++) {
            const int V0 = 2 * kc, V1 = 2 * kc + 1;
            const int r0 = ((V0 >> 2) << 4) | ((V0 & 3) << 2);
            const int r1 = ((V1 >> 2) << 4) | ((V1 & 3) << 2);
#define PSEL(i) ((i) < 16 ? pA[(i) & 15] : pB[(i) & 15])
            unsigned a0 = pk2(PSEL(r0 + 0), PSEL(r0 + 1));
            unsigned a1 = pk2(PSEL(r0 + 2), PSEL(r0 + 3));
            unsigned b0 = pk2(PSEL(r1 + 0), PSEL(r1 + 1));
            unsigned b1 = pk2(PSEL(r1 + 2), PSEL(r1 + 3));
#undef PSEL
            unsigned k0 = hi ? b0 : a0, k1 = hi ? b1 : a1;   // keep (own u-range)
            unsigned s0 = hi ? a0 : b0, s1 = hi ? a1 : b1;   // send to lane^32
            unsigned g0 = (unsigned)__shfl_xor((int)s0, 32);
            unsigned g1 = (unsigned)__shfl_xor((int)s1, 32);
            union { unsigned u[4]; bf16x8 v; } U;
            U.u[0] = hi ? g0 : k0;
            U.u[1] = hi ? g1 : k1;
            U.u[2] = hi ? k0 : g0;
            U.u[3] = hi ? k1 : g1;
            pf[kc] = U.v;
        }

        // ---- O += P @ V : V as B-operand direct from vtg [b][d][t] ----
        #pragma unroll
        for (int kc = 0; kc < 4; kc++) {
            #pragma unroll
            for (int nb = 0; nb < 4; nb++) {
                bf16x8 vf = *reinterpret_cast<const bf16x8*>(
                    &vb[(long)(nb * 32 + c31) * T_SEQ + kv0 + kc * 16 + hi8]);
                accO[nb] = __builtin_amdgcn_mfma_f32_32x32x16_bf16(
                    pf[kc], vf, accO[nb], 0, 0, 0);
            }
        }
    }

    // ---- dump wave partial (D layout: col=l&31, row=(r&3)+8*(r>>2)+4*hi) ----
    #pragma unroll
    for (int nb = 0; nb < 4; nb++)
        #pragma unroll
        for (int r = 0; r < 16; r++)
            Lacc[w][(r & 3) + 8 * (r >> 2) + hi4][nb * 32 + c31] = accO[nb][r];
    if (l < 32) { Lm[w][c31] = mrow; Ll[w][c31] = lsum; }
    __syncthreads();

    // ---- merge 4 partials: thread t -> row t>>3, cols (t&7)*16 .. +15 ----
    {
        const int row = tid >> 3;
        const int c0  = (tid & 7) * 16;
        float m0 = Lm[0][row], m1 = Lm[1][row], m2 = Lm[2][row], m3 = Lm[3][row];
        float ms = fmaxf(fmaxf(m0, m1), fmaxf(m2, m3));
        float f0 = exp2f(m0 - ms), f1 = exp2f(m1 - ms);
        float f2 = exp2f(m2 - ms), f3 = exp2f(m3 - ms);
        float L = Ll[0][row] * f0 + Ll[1][row] * f1 + Ll[2][row] * f2 + Ll[3][row] * f3;
        float inv = 1.0f / L;
        float* op = &out[((long)b * T_SEQ + q0 + row) * HS + c0];
        #pragma unroll
        for (int j = 0; j < 16; j++) {
            float o = Lacc[0][row][c0 + j] * f0 + Lacc[1][row][c0 + j] * f1
                    + Lacc[2][row][c0 + j] * f2 + Lacc[3][row][c0 + j] * f3;
            op[j] = o * inv;
        }
    }
}

// ---------------- launch ------------------------------------------------------
extern "C" void kernel_launch(void* const* d_in, const int* in_sizes, int n_in,
                              void* d_out, int out_size, void* d_ws, size_t ws_size,
                              hipStream_t stream) {
    const float* x  = (const float*)d_in[0];
    const float* Wk = (const float*)d_in[1];
    const float* Wq = (const float*)d_in[2];
    const float* Wv = (const float*)d_in[3];
    float* out = (float*)d_out;

    char* ws = (char*)d_ws;
    short* Wt  = (short*)ws;                                  // 1.5 MB (swizzled panels)
    short* qg  = (short*)(ws + 1572864);                      // 4 MB
    short* kg  = (short*)(ws + 1572864 + 4194304);            // 4 MB
    short* vtg = (short*)(ws + 1572864 + 8388608);            // 4 MB

    wt_kernel  <<<3072, 256, 0, stream>>>(Wq, Wk, Wv, Wt);
    proj_kernel<<<768,  256, 0, stream>>>(x, Wt, qg, kg, vtg);
    attn_kernel<<<512,  256, 0, stream>>>(qg, kg, vtg, out);
}

// Round 8
// 163.529 us; speedup vs baseline: 1.8724x; 1.0092x over previous
//
#include <hip/hip_runtime.h>
#include <hip/hip_bf16.h>

#define T_SEQ 4096
#define NB 4
#define CEMB 2048
#define HS 128

typedef __attribute__((ext_vector_type(8))) short bf16x8;
typedef __attribute__((ext_vector_type(4))) float f32x4;
typedef __attribute__((ext_vector_type(16))) float f32x16;

__device__ inline short f2bf(float f) {
    union { float f; unsigned u; } v; v.f = f;
    unsigned r = v.u + 0x7FFFu + ((v.u >> 16) & 1u);   // RNE
    return (short)(r >> 16);
}

__device__ inline unsigned pk2(float lo, float hi) {
    return ((unsigned)(unsigned short)f2bf(lo)) | (((unsigned)(unsigned short)f2bf(hi)) << 16);
}

__device__ inline void gld16(const void* gsrc, void* lds) {
    __builtin_amdgcn_global_load_lds(
        (const __attribute__((address_space(1))) unsigned*)gsrc,
        (__attribute__((address_space(3))) unsigned*)lds, 16, 0, 0);
}

// ---------------- kernel 1: W -> pre-swizzled bf16 LDS-image panels ----------
__global__ __launch_bounds__(256) void wt_kernel(
    const float* __restrict__ Wq, const float* __restrict__ Wk,
    const float* __restrict__ Wv, short* __restrict__ Wt) {
    int d = blockIdx.x * 256 + threadIdx.x;     // 3*32*8192 = 786432
    int mat = d >> 18;
    int rm  = d & 262143;
    int s   = rm >> 13;                         // panel 0..31
    int e   = rm & 8191;
    int p   = e * 2;
    int n   = p >> 7;
    int lin = p ^ ((n & 7) << 4);
    int kk  = (lin & 127) >> 1;
    int k   = s * 64 + kk;
    const float* W = (mat == 0) ? Wq : (mat == 1) ? Wk : Wv;
    Wt[d] = f2bf(W[k * HS + n]);
}

// ---------------- kernel 2: q/k/v projection, 3-buffer counted-vmcnt pipeline
// grid 768, XCD-chunked: wk = (bid&7)*96 + (bid>>3); mat = wk%3; mtile = wk/3.
// Depth-2 prefetch of both the W panel (LDS) and x (registers); barrier is
// raw s_barrier with s_waitcnt vmcnt(8) -- loads for the NEXT iteration stay
// in flight across the barrier (T4). q pre-scaled by log2(e)/sqrt(2048).
__global__ __launch_bounds__(256, 3) void proj_kernel(
    const float* __restrict__ x, const short* __restrict__ Wt,
    short* __restrict__ qg, short* __restrict__ kg, short* __restrict__ vtg) {
    __shared__ short Wlds[3][8192];   // 3 x 16KB panels

    const int tid = threadIdx.x;
    const int w   = tid >> 6;
    const int l   = tid & 63;
    const int lg  = l >> 4;
    const int lr  = l & 15;

    const int bid = blockIdx.x;
    const int wk  = (bid & 7) * 96 + (bid >> 3);   // same-XCD chunking
    const int mat = wk % 3;
    const int m0  = (wk / 3) * 64;

    const short* Wp = Wt + (long)mat * 262144;

    f32x4 acc[8];
    #pragma unroll
    for (int b = 0; b < 8; b++) acc[b] = (f32x4){0.f, 0.f, 0.f, 0.f};

    const float* xrow = x + (long)(m0 + w * 16 + lr) * CEMB;
    const int sw = (lr & 7) << 4;

    float4 xs[3][4];   // all indices compile-time constant (no scratch)

#define STAGE(S, B) do {                                                   \
        const short* gp_ = Wp + (long)(S) * 8192 + (long)(w * 4) * 512 + l * 8; \
        gld16(gp_,        &Wlds[B][(w * 4 + 0) * 512]);                    \
        gld16(gp_ + 512,  &Wlds[B][(w * 4 + 1) * 512]);                    \
        gld16(gp_ + 1024, &Wlds[B][(w * 4 + 2) * 512]);                    \
        gld16(gp_ + 1536, &Wlds[B][(w * 4 + 3) * 512]);                    \
    } while (0)

#define LOADX(S, B) do {                                                   \
        const float* xn_ = xrow + (S) * 64;                                \
        xs[B][0] = *reinterpret_cast<const float4*>(xn_ + lg * 8);         \
        xs[B][1] = *reinterpret_cast<const float4*>(xn_ + lg * 8 + 4);     \
        xs[B][2] = *reinterpret_cast<const float4*>(xn_ + 32 + lg * 8);    \
        xs[B][3] = *reinterpret_cast<const float4*>(xn_ + 32 + lg * 8 + 4);\
    } while (0)

    // prologue: panels 0,1 + x blocks 0,1 in flight (oldest 8 = stage0+xs0)
    STAGE(0, 0);
    LOADX(0, 0);
    STAGE(1, 1);
    LOADX(1, 1);

#define STEP(S, B0, B2) do {                                               \
        asm volatile("s_waitcnt vmcnt(8) lgkmcnt(0)\n\ts_barrier" ::: "memory"); \
        if ((S) + 2 < 32) { STAGE((S) + 2, B2); LOADX((S) + 2, B2); }      \
        bf16x8 a0, a1;                                                     \
        a0[0] = f2bf(xs[B0][0].x); a0[1] = f2bf(xs[B0][0].y);              \
        a0[2] = f2bf(xs[B0][0].z); a0[3] = f2bf(xs[B0][0].w);              \
        a0[4] = f2bf(xs[B0][1].x); a0[5] = f2bf(xs[B0][1].y);              \
        a0[6] = f2bf(xs[B0][1].z); a0[7] = f2bf(xs[B0][1].w);              \
        a1[0] = f2bf(xs[B0][2].x); a1[1] = f2bf(xs[B0][2].y);              \
        a1[2] = f2bf(xs[B0][2].z); a1[3] = f2bf(xs[B0][2].w);              \
        a1[4] = f2bf(xs[B0][3].x); a1[5] = f2bf(xs[B0][3].y);              \
        a1[6] = f2bf(xs[B0][3].z); a1[7] = f2bf(xs[B0][3].w);              \
        const char* lbase_ = (const char*)&Wlds[B0][0];                    \
        _Pragma("unroll")                                                  \
        for (int nt = 0; nt < 8; nt++) {                                   \
            int off_ = (((nt * 16 + lr) * 128 + lg * 16)) ^ sw;            \
            bf16x8 bfr_ = *reinterpret_cast<const bf16x8*>(lbase_ + off_); \
            acc[nt] = __builtin_amdgcn_mfma_f32_16x16x32_bf16(             \
                a0, bfr_, acc[nt], 0, 0, 0);                               \
        }                                                                  \
        _Pragma("unroll")                                                  \
        for (int nt = 0; nt < 8; nt++) {                                   \
            int off_ = (((nt * 16 + lr) * 128 + lg * 16 + 64)) ^ sw;       \
            bf16x8 bfr_ = *reinterpret_cast<const bf16x8*>(lbase_ + off_); \
            acc[nt] = __builtin_amdgcn_mfma_f32_16x16x32_bf16(             \
                a1, bfr_, acc[nt], 0, 0, 0);                               \
        }                                                                  \
    } while (0)

    for (int s = 0; s < 30; s += 3) {
        STEP(s, 0, 2);
        STEP(s + 1, 1, 0);
        STEP(s + 2, 2, 1);
    }
    STEP(30, 0, 2);
    STEP(31, 1, 0);

#undef STEP
#undef LOADX
#undef STAGE

    if (mat == 0) {
        const float scale = 0.0318793851f;  // log2(e) / sqrt(2048), folded into q
        #pragma unroll
        for (int nt = 0; nt < 8; nt++)
            #pragma unroll
            for (int r = 0; r < 4; r++) {
                int row = m0 + w * 16 + lg * 4 + r;
                qg[(long)row * HS + nt * 16 + lr] = f2bf(acc[nt][r] * scale);
            }
    } else if (mat == 1) {
        #pragma unroll
        for (int nt = 0; nt < 8; nt++)
            #pragma unroll
            for (int r = 0; r < 4; r++) {
                int row = m0 + w * 16 + lg * 4 + r;
                kg[(long)row * HS + nt * 16 + lr] = f2bf(acc[nt][r]);
            }
    } else {
        #pragma unroll
        for (int nt = 0; nt < 8; nt++)
            #pragma unroll
            for (int r = 0; r < 4; r++) {
                int row = m0 + w * 16 + lg * 4 + r;
                int b   = row >> 12;
                int tl  = row & 4095;
                vtg[(long)b * (HS * T_SEQ) + (long)(nt * 16 + lr) * T_SEQ + tl]
                    = f2bf(acc[nt][r]);
            }
    }
}

// ---------------- kernel 3: flash attention, swapped-QK 32x32, KV-split ------
// (unchanged from round 7 -- verified at ~50 us timed)
__global__ __launch_bounds__(256, 2) void attn_kernel(
    const short* __restrict__ qg, const short* __restrict__ kg,
    const short* __restrict__ vtg, float* __restrict__ out) {
    __shared__ float Lacc[4][32][128];   // 64 KB merge buffer
    __shared__ float Lm[4][32];
    __shared__ float Ll[4][32];

    const int tid = threadIdx.x;
    const int w   = tid >> 6;      // wave = kv-split index
    const int l   = tid & 63;
    const int c31 = l & 31;
    const int hi  = l >> 5;
    const int hi4 = hi << 2;
    const int hi8 = hi << 3;

    const int bid = blockIdx.x;
    const int xcd = bid & 7;
    const int idx = bid >> 3;                        // 0..63
    const int b   = xcd >> 1;                        // batch pinned to XCD pair
    const int qt  = 127 - ((idx << 1) | (xcd & 1));  // 0..127, descending
    const int q0  = qt * 32;
    const int qrow = q0 + c31;                       // this lane's q-row

    const short* kb = kg  + (long)b * T_SEQ * HS;
    const short* vb = vtg + (long)b * HS * T_SEQ;

    // Q as B-operand: col = l&31 = q-row, k = kc*16 + hi*8 + j
    bf16x8 qf[8];
    #pragma unroll
    for (int kc = 0; kc < 8; kc++)
        qf[kc] = *reinterpret_cast<const bf16x8*>(
            &qg[(long)(b * T_SEQ + qrow) * HS + kc * 16 + hi8]);

    f32x16 accO[4];
    #pragma unroll
    for (int nb = 0; nb < 4; nb++)
        #pragma unroll
        for (int i = 0; i < 16; i++) accO[nb][i] = 0.f;
    float mrow = -__builtin_inff();
    float lsum = 0.f;

    const int ntk = (qt >> 1) + 1;

    #pragma unroll 1
    for (int t = w; t < ntk; t += 4) {
        const int kv0 = t * 64;

        // ---- S^T = K @ Q^T : two 32-kv blocks ----
        f32x16 SA, SB;
        #pragma unroll
        for (int i = 0; i < 16; i++) { SA[i] = 0.f; SB[i] = 0.f; }
        #pragma unroll
        for (int kc = 0; kc < 8; kc++) {
            bf16x8 ka = *reinterpret_cast<const bf16x8*>(
                &kb[(long)(kv0 + c31) * HS + kc * 16 + hi8]);
            bf16x8 kbf = *reinterpret_cast<const bf16x8*>(
                &kb[(long)(kv0 + 32 + c31) * HS + kc * 16 + hi8]);
            SA = __builtin_amdgcn_mfma_f32_32x32x16_bf16(ka,  qf[kc], SA, 0, 0, 0);
            SB = __builtin_amdgcn_mfma_f32_32x32x16_bf16(kbf, qf[kc], SB, 0, 0, 0);
        }

        float pA[16], pB[16];
        #pragma unroll
        for (int r = 0; r < 16; r++) { pA[r] = SA[r]; pB[r] = SB[r]; }

        // ---- causal mask (boundary tiles only) ----
        if (kv0 + 63 > q0) {
            #pragma unroll
            for (int r = 0; r < 16; r++) {
                int kr = kv0 + (r & 3) + 8 * (r >> 2) + hi4;
                pA[r] = (kr > qrow)      ? -__builtin_inff() : pA[r];
                pB[r] = (kr + 32 > qrow) ? -__builtin_inff() : pB[r];
            }
        }

        // ---- in-lane softmax (scores in log2 units; q pre-scaled) ----
        float t16[16];
        #pragma unroll
        for (int r = 0; r < 16; r++) t16[r] = fmaxf(pA[r], pB[r]);
        #pragma unroll
        for (int s2 = 8; s2 >= 1; s2 >>= 1)
            #pragma unroll
            for (int r = 0; r < 8; r++)
                if (r < s2) t16[r] = fmaxf(t16[r], t16[r + s2]);
        float mt   = fmaxf(t16[0], __shfl_xor(t16[0], 32));
        float mnew = fmaxf(mrow, mt);
        float fac  = exp2f(mrow - mnew);

        #pragma unroll
        for (int r = 0; r < 16; r++) {
            pA[r] = exp2f(pA[r] - mnew);
            pB[r] = exp2f(pB[r] - mnew);
        }
        float s16[16];
        #pragma unroll
        for (int r = 0; r < 16; r++) s16[r] = pA[r] + pB[r];
        #pragma unroll
        for (int s2 = 8; s2 >= 1; s2 >>= 1)
            #pragma unroll
            for (int r = 0; r < 8; r++)
                if (r < s2) s16[r] += s16[r + s2];
        float ts = s16[0] + __shfl_xor(s16[0], 32);
        lsum = lsum * fac + ts;
        mrow = mnew;

        #pragma unroll
        for (int nb = 0; nb < 4; nb++)
            #pragma unroll
            for (int i = 0; i < 16; i++) accO[nb][i] *= fac;

        // ---- pack P into PV A-frags: keep/send + lane^32 exchange ----
        bf16x8 pf[4];
        #pragma unroll
        for (int kc = 0; kc < 4; kc++) {
            const int V0 = 2 * kc, V1 = 2 * kc + 1;
            const int r0 = ((V0 >> 2) << 4) | ((V0 & 3) << 2);
            const int r1 = ((V1 >> 2) << 4) | ((V1 & 3) << 2);
#define PSEL(i) ((i) < 16 ? pA[(i) & 15] : pB[(i) & 15])
            unsigned a0 = pk2(PSEL(r0 + 0), PSEL(r0 + 1));
            unsigned a1 = pk2(PSEL(r0 + 2), PSEL(r0 + 3));
            unsigned b0 = pk2(PSEL(r1 + 0), PSEL(r1 + 1));
            unsigned b1 = pk2(PSEL(r1 + 2), PSEL(r1 + 3));
#undef PSEL
            unsigned k0 = hi ? b0 : a0, k1 = hi ? b1 : a1;
            unsigned s0 = hi ? a0 : b0, s1 = hi ? a1 : b1;
            unsigned g0 = (unsigned)__shfl_xor((int)s0, 32);
            unsigned g1 = (unsigned)__shfl_xor((int)s1, 32);
            union { unsigned u[4]; bf16x8 v; } U;
            U.u[0] = hi ? g0 : k0;
            U.u[1] = hi ? g1 : k1;
            U.u[2] = hi ? k0 : g0;
            U.u[3] = hi ? k1 : g1;
            pf[kc] = U.v;
        }

        // ---- O += P @ V : V as B-operand direct from vtg [b][d][t] ----
        #pragma unroll
        for (int kc = 0; kc < 4; kc++) {
            #pragma unroll
            for (int nb = 0; nb < 4; nb++) {
                bf16x8 vf = *reinterpret_cast<const bf16x8*>(
                    &vb[(long)(nb * 32 + c31) * T_SEQ + kv0 + kc * 16 + hi8]);
                accO[nb] = __builtin_amdgcn_mfma_f32_32x32x16_bf16(
                    pf[kc], vf, accO[nb], 0, 0, 0);
            }
        }
    }

    // ---- dump wave partial (D layout: col=l&31, row=(r&3)+8*(r>>2)+4*hi) ----
    #pragma unroll
    for (int nb = 0; nb < 4; nb++)
        #pragma unroll
        for (int r = 0; r < 16; r++)
            Lacc[w][(r & 3) + 8 * (r >> 2) + hi4][nb * 32 + c31] = accO[nb][r];
    if (l < 32) { Lm[w][c31] = mrow; Ll[w][c31] = lsum; }
    __syncthreads();

    // ---- merge 4 partials: thread t -> row t>>3, cols (t&7)*16 .. +15 ----
    {
        const int row = tid >> 3;
        const int c0  = (tid & 7) * 16;
        float m0 = Lm[0][row], m1 = Lm[1][row], m2 = Lm[2][row], m3 = Lm[3][row];
        float ms = fmaxf(fmaxf(m0, m1), fmaxf(m2, m3));
        float f0 = exp2f(m0 - ms), f1 = exp2f(m1 - ms);
        float f2 = exp2f(m2 - ms), f3 = exp2f(m3 - ms);
        float L = Ll[0][row] * f0 + Ll[1][row] * f1 + Ll[2][row] * f2 + Ll[3][row] * f3;
        float inv = 1.0f / L;
        float* op = &out[((long)b * T_SEQ + q0 + row) * HS + c0];
        #pragma unroll
        for (int j = 0; j < 16; j++) {
            float o = Lacc[0][row][c0 + j] * f0 + Lacc[1][row][c0 + j] * f1
                    + Lacc[2][row][c0 + j] * f2 + Lacc[3][row][c0 + j] * f3;
            op[j] = o * inv;
        }
    }
}

// ---------------- launch ------------------------------------------------------
extern "C" void kernel_launch(void* const* d_in, const int* in_sizes, int n_in,
                              void* d_out, int out_size, void* d_ws, size_t ws_size,
                              hipStream_t stream) {
    const float* x  = (const float*)d_in[0];
    const float* Wk = (const float*)d_in[1];
    const float* Wq = (const float*)d_in[2];
    const float* Wv = (const float*)d_in[3];
    float* out = (float*)d_out;

    char* ws = (char*)d_ws;
    short* Wt  = (short*)ws;                                  // 1.5 MB (swizzled panels)
    short* qg  = (short*)(ws + 1572864);                      // 4 MB
    short* kg  = (short*)(ws + 1572864 + 4194304);            // 4 MB
    short* vtg = (short*)(ws + 1572864 + 8388608);            // 4 MB

    wt_kernel  <<<3072, 256, 0, stream>>>(Wq, Wk, Wv, Wt);
    proj_kernel<<<768,  256, 0, stream>>>(x, Wt, qg, kg, vtg);
    attn_kernel<<<512,  256, 0, stream>>>(qg, kg, vtg, out);
}

// Round 9
// 162.094 us; speedup vs baseline: 1.8890x; 1.0089x over previous
//
#include <hip/hip_runtime.h>
#include <hip/hip_bf16.h>

#define T_SEQ 4096
#define NB 4
#define CEMB 2048
#define HS 128

typedef __attribute__((ext_vector_type(8))) short bf16x8;
typedef __attribute__((ext_vector_type(4))) float f32x4;
typedef __attribute__((ext_vector_type(16))) float f32x16;

__device__ inline short f2bf(float f) {
    union { float f; unsigned u; } v; v.f = f;
    unsigned r = v.u + 0x7FFFu + ((v.u >> 16) & 1u);   // RNE
    return (short)(r >> 16);
}

__device__ inline unsigned pk2(float lo, float hi) {
    unsigned r;
    asm("v_cvt_pk_bf16_f32 %0, %1, %2" : "=v"(r) : "v"(lo), "v"(hi));
    return r;
}

__device__ inline void gld16(const void* gsrc, void* lds) {
    __builtin_amdgcn_global_load_lds(
        (const __attribute__((address_space(1))) unsigned*)gsrc,
        (__attribute__((address_space(3))) unsigned*)lds, 16, 0, 0);
}

// ---------------- kernel 1: W -> pre-swizzled bf16 LDS-image panels ----------
__global__ __launch_bounds__(256) void wt_kernel(
    const float* __restrict__ Wq, const float* __restrict__ Wk,
    const float* __restrict__ Wv, short* __restrict__ Wt) {
    int d = blockIdx.x * 256 + threadIdx.x;     // 3*32*8192 = 786432
    int mat = d >> 18;
    int rm  = d & 262143;
    int s   = rm >> 13;                         // panel 0..31
    int e   = rm & 8191;
    int p   = e * 2;
    int n   = p >> 7;
    int lin = p ^ ((n & 7) << 4);
    int kk  = (lin & 127) >> 1;
    int k   = s * 64 + kk;
    const float* W = (mat == 0) ? Wq : (mat == 1) ? Wk : Wv;
    Wt[d] = f2bf(W[k * HS + n]);
}

// ---------------- kernel 2: q/k/v projection (unchanged from round 8) --------
__global__ __launch_bounds__(256, 3) void proj_kernel(
    const float* __restrict__ x, const short* __restrict__ Wt,
    short* __restrict__ qg, short* __restrict__ kg, short* __restrict__ vtg) {
    __shared__ short Wlds[3][8192];   // 3 x 16KB panels

    const int tid = threadIdx.x;
    const int w   = tid >> 6;
    const int l   = tid & 63;
    const int lg  = l >> 4;
    const int lr  = l & 15;

    const int bid = blockIdx.x;
    const int wk  = (bid & 7) * 96 + (bid >> 3);   // same-XCD chunking
    const int mat = wk % 3;
    const int m0  = (wk / 3) * 64;

    const short* Wp = Wt + (long)mat * 262144;

    f32x4 acc[8];
    #pragma unroll
    for (int b = 0; b < 8; b++) acc[b] = (f32x4){0.f, 0.f, 0.f, 0.f};

    const float* xrow = x + (long)(m0 + w * 16 + lr) * CEMB;
    const int sw = (lr & 7) << 4;

    float4 xs[3][4];

#define STAGE(S, B) do {                                                   \
        const short* gp_ = Wp + (long)(S) * 8192 + (long)(w * 4) * 512 + l * 8; \
        gld16(gp_,        &Wlds[B][(w * 4 + 0) * 512]);                    \
        gld16(gp_ + 512,  &Wlds[B][(w * 4 + 1) * 512]);                    \
        gld16(gp_ + 1024, &Wlds[B][(w * 4 + 2) * 512]);                    \
        gld16(gp_ + 1536, &Wlds[B][(w * 4 + 3) * 512]);                    \
    } while (0)

#define LOADX(S, B) do {                                                   \
        const float* xn_ = xrow + (S) * 64;                                \
        xs[B][0] = *reinterpret_cast<const float4*>(xn_ + lg * 8);         \
        xs[B][1] = *reinterpret_cast<const float4*>(xn_ + lg * 8 + 4);     \
        xs[B][2] = *reinterpret_cast<const float4*>(xn_ + 32 + lg * 8);    \
        xs[B][3] = *reinterpret_cast<const float4*>(xn_ + 32 + lg * 8 + 4);\
    } while (0)

    STAGE(0, 0);
    LOADX(0, 0);
    STAGE(1, 1);
    LOADX(1, 1);

#define STEP(S, B0, B2) do {                                               \
        asm volatile("s_waitcnt vmcnt(8) lgkmcnt(0)\n\ts_barrier" ::: "memory"); \
        if ((S) + 2 < 32) { STAGE((S) + 2, B2); LOADX((S) + 2, B2); }      \
        bf16x8 a0, a1;                                                     \
        a0[0] = f2bf(xs[B0][0].x); a0[1] = f2bf(xs[B0][0].y);              \
        a0[2] = f2bf(xs[B0][0].z); a0[3] = f2bf(xs[B0][0].w);              \
        a0[4] = f2bf(xs[B0][1].x); a0[5] = f2bf(xs[B0][1].y);              \
        a0[6] = f2bf(xs[B0][1].z); a0[7] = f2bf(xs[B0][1].w);              \
        a1[0] = f2bf(xs[B0][2].x); a1[1] = f2bf(xs[B0][2].y);              \
        a1[2] = f2bf(xs[B0][2].z); a1[3] = f2bf(xs[B0][2].w);              \
        a1[4] = f2bf(xs[B0][3].x); a1[5] = f2bf(xs[B0][3].y);              \
        a1[6] = f2bf(xs[B0][3].z); a1[7] = f2bf(xs[B0][3].w);              \
        const char* lbase_ = (const char*)&Wlds[B0][0];                    \
        _Pragma("unroll")                                                  \
        for (int nt = 0; nt < 8; nt++) {                                   \
            int off_ = (((nt * 16 + lr) * 128 + lg * 16)) ^ sw;            \
            bf16x8 bfr_ = *reinterpret_cast<const bf16x8*>(lbase_ + off_); \
            acc[nt] = __builtin_amdgcn_mfma_f32_16x16x32_bf16(             \
                a0, bfr_, acc[nt], 0, 0, 0);                               \
        }                                                                  \
        _Pragma("unroll")                                                  \
        for (int nt = 0; nt < 8; nt++) {                                   \
            int off_ = (((nt * 16 + lr) * 128 + lg * 16 + 64)) ^ sw;       \
            bf16x8 bfr_ = *reinterpret_cast<const bf16x8*>(lbase_ + off_); \
            acc[nt] = __builtin_amdgcn_mfma_f32_16x16x32_bf16(             \
                a1, bfr_, acc[nt], 0, 0, 0);                               \
        }                                                                  \
    } while (0)

    for (int s = 0; s < 30; s += 3) {
        STEP(s, 0, 2);
        STEP(s + 1, 1, 0);
        STEP(s + 2, 2, 1);
    }
    STEP(30, 0, 2);
    STEP(31, 1, 0);

#undef STEP
#undef LOADX
#undef STAGE

    if (mat == 0) {
        const float scale = 0.0318793851f;  // log2(e) / sqrt(2048), folded into q
        #pragma unroll
        for (int nt = 0; nt < 8; nt++)
            #pragma unroll
            for (int r = 0; r < 4; r++) {
                int row = m0 + w * 16 + lg * 4 + r;
                qg[(long)row * HS + nt * 16 + lr] = f2bf(acc[nt][r] * scale);
            }
    } else if (mat == 1) {
        #pragma unroll
        for (int nt = 0; nt < 8; nt++)
            #pragma unroll
            for (int r = 0; r < 4; r++) {
                int row = m0 + w * 16 + lg * 4 + r;
                kg[(long)row * HS + nt * 16 + lr] = f2bf(acc[nt][r]);
            }
    } else {
        #pragma unroll
        for (int nt = 0; nt < 8; nt++)
            #pragma unroll
            for (int r = 0; r < 4; r++) {
                int row = m0 + w * 16 + lg * 4 + r;
                int b   = row >> 12;
                int tl  = row & 4095;
                vtg[(long)b * (HS * T_SEQ) + (long)(nt * 16 + lr) * T_SEQ + tl]
                    = f2bf(acc[nt][r]);
            }
    }
}

// ---------------- kernel 3: flash attention v3 --------------------------------
// swapped-QK 32x32, KV-split 4 waves/block. New vs R7: early V-load issue
// (half at tile start, half mid-softmax), cvt_pk bf16 pack, exact
// defer-rescale (skip accO rescale when tile max doesn't grow), s_setprio
// around MFMA clusters. Q re-read from L1 per tile to bound VGPR (~240 peak).
__global__ __launch_bounds__(256, 2) void attn_kernel(
    const short* __restrict__ qg, const short* __restrict__ kg,
    const short* __restrict__ vtg, float* __restrict__ out) {
    __shared__ float Lacc[4][32][128];   // 64 KB merge buffer
    __shared__ float Lm[4][32];
    __shared__ float Ll[4][32];

    const int tid = threadIdx.x;
    const int w   = tid >> 6;      // wave = kv-split index
    const int l   = tid & 63;
    const int c31 = l & 31;
    const int hi  = l >> 5;
    const int hi4 = hi << 2;
    const int hi8 = hi << 3;

    const int bid = blockIdx.x;
    const int xcd = bid & 7;
    const int idx = bid >> 3;                        // 0..63
    const int b   = xcd >> 1;                        // batch pinned to XCD pair
    const int qt  = 127 - ((idx << 1) | (xcd & 1));  // 0..127, descending
    const int q0  = qt * 32;
    const int qrow = q0 + c31;                       // this lane's q-row

    const short* kb = kg  + (long)b * T_SEQ * HS;
    const short* vb = vtg + (long)b * HS * T_SEQ;
    const short* qb = qg  + (long)(b * T_SEQ + qrow) * HS;

    f32x16 accO[4];
    #pragma unroll
    for (int nb = 0; nb < 4; nb++)
        #pragma unroll
        for (int i = 0; i < 16; i++) accO[nb][i] = 0.f;
    float mrow = -__builtin_inff();
    float lsum = 0.f;

    const int ntk = (qt >> 1) + 1;

    #pragma unroll 1
    for (int t = w; t < ntk; t += 4) {
        const int kv0 = t * 64;

        // ---- issue K frags (rows c31 and 32+c31) ----
        bf16x8 ka[8], kb2[8];
        #pragma unroll
        for (int kc = 0; kc < 8; kc++)
            ka[kc] = *reinterpret_cast<const bf16x8*>(
                &kb[(long)(kv0 + c31) * HS + kc * 16 + hi8]);
        #pragma unroll
        for (int kc = 0; kc < 8; kc++)
            kb2[kc] = *reinterpret_cast<const bf16x8*>(
                &kb[(long)(kv0 + 32 + c31) * HS + kc * 16 + hi8]);

        // ---- Q frags (L1-hot re-read, keeps VGPR bounded) ----
        bf16x8 qf[8];
        #pragma unroll
        for (int kc = 0; kc < 8; kc++)
            qf[kc] = *reinterpret_cast<const bf16x8*>(&qb[kc * 16 + hi8]);

        // ---- issue first half of V early (consumed by PV kc=0,1) ----
        bf16x8 vfA[2][4];
        #pragma unroll
        for (int kc = 0; kc < 2; kc++)
            #pragma unroll
            for (int nb = 0; nb < 4; nb++)
                vfA[kc][nb] = *reinterpret_cast<const bf16x8*>(
                    &vb[(long)(nb * 32 + c31) * T_SEQ + kv0 + kc * 16 + hi8]);

        // ---- S^T = K @ Q^T ----
        f32x16 SA, SB;
        #pragma unroll
        for (int i = 0; i < 16; i++) { SA[i] = 0.f; SB[i] = 0.f; }
        __builtin_amdgcn_s_setprio(1);
        #pragma unroll
        for (int kc = 0; kc < 8; kc++) {
            SA = __builtin_amdgcn_mfma_f32_32x32x16_bf16(ka[kc],  qf[kc], SA, 0, 0, 0);
            SB = __builtin_amdgcn_mfma_f32_32x32x16_bf16(kb2[kc], qf[kc], SB, 0, 0, 0);
        }
        __builtin_amdgcn_s_setprio(0);

        float pA[16], pB[16];
        #pragma unroll
        for (int r = 0; r < 16; r++) { pA[r] = SA[r]; pB[r] = SB[r]; }

        // ---- causal mask (boundary tiles only) ----
        if (kv0 + 63 > q0) {
            #pragma unroll
            for (int r = 0; r < 16; r++) {
                int kr = kv0 + (r & 3) + 8 * (r >> 2) + hi4;
                pA[r] = (kr > qrow)      ? -__builtin_inff() : pA[r];
                pB[r] = (kr + 32 > qrow) ? -__builtin_inff() : pB[r];
            }
        }

        // ---- max tree (in-lane, then 1 cross-shfl) ----
        float t16[16];
        #pragma unroll
        for (int r = 0; r < 16; r++) t16[r] = fmaxf(pA[r], pB[r]);
        #pragma unroll
        for (int s2 = 8; s2 >= 1; s2 >>= 1)
            #pragma unroll
            for (int r = 0; r < 8; r++)
                if (r < s2) t16[r] = fmaxf(t16[r], t16[r + s2]);
        float mt = fmaxf(t16[0], __shfl_xor(t16[0], 32));

        // ---- exact defer-rescale: only touch accO when the max grows ----
        if (__any(mt > mrow)) {
            float mnew = fmaxf(mrow, mt);
            float fac  = exp2f(mrow - mnew);   // 1.0 for lanes that didn't grow
            lsum *= fac;
            #pragma unroll
            for (int nb = 0; nb < 4; nb++)
                #pragma unroll
                for (int i = 0; i < 16; i++) accO[nb][i] *= fac;
            mrow = mnew;
        }

        // ---- issue second half of V (covered by exp2/sum/pack below) ----
        bf16x8 vfB[2][4];
        #pragma unroll
        for (int kc = 0; kc < 2; kc++)
            #pragma unroll
            for (int nb = 0; nb < 4; nb++)
                vfB[kc][nb] = *reinterpret_cast<const bf16x8*>(
                    &vb[(long)(nb * 32 + c31) * T_SEQ + kv0 + (kc + 2) * 16 + hi8]);

        // ---- P = exp2(S - m) ----
        #pragma unroll
        for (int r = 0; r < 16; r++) {
            pA[r] = exp2f(pA[r] - mrow);
            pB[r] = exp2f(pB[r] - mrow);
        }
        float s16[16];
        #pragma unroll
        for (int r = 0; r < 16; r++) s16[r] = pA[r] + pB[r];
        #pragma unroll
        for (int s2 = 8; s2 >= 1; s2 >>= 1)
            #pragma unroll
            for (int r = 0; r < 8; r++)
                if (r < s2) s16[r] += s16[r + s2];
        lsum += s16[0] + __shfl_xor(s16[0], 32);

        // ---- pack P into PV A-frags (cvt_pk + lane^32 exchange) ----
        bf16x8 pf[4];
        #pragma unroll
        for (int kc = 0; kc < 4; kc++) {
            const int V0 = 2 * kc, V1 = 2 * kc + 1;
            const int r0 = ((V0 >> 2) << 4) | ((V0 & 3) << 2);
            const int r1 = ((V1 >> 2) << 4) | ((V1 & 3) << 2);
#define PSEL(i) ((i) < 16 ? pA[(i) & 15] : pB[(i) & 15])
            unsigned a0 = pk2(PSEL(r0 + 0), PSEL(r0 + 1));
            unsigned a1 = pk2(PSEL(r0 + 2), PSEL(r0 + 3));
            unsigned b0 = pk2(PSEL(r1 + 0), PSEL(r1 + 1));
            unsigned b1 = pk2(PSEL(r1 + 2), PSEL(r1 + 3));
#undef PSEL
            unsigned k0 = hi ? b0 : a0, k1 = hi ? b1 : a1;
            unsigned s0 = hi ? a0 : b0, s1 = hi ? a1 : b1;
            unsigned g0 = (unsigned)__shfl_xor((int)s0, 32);
            unsigned g1 = (unsigned)__shfl_xor((int)s1, 32);
            union { unsigned u[4]; bf16x8 v; } U;
            U.u[0] = hi ? g0 : k0;
            U.u[1] = hi ? g1 : k1;
            U.u[2] = hi ? k0 : g0;
            U.u[3] = hi ? k1 : g1;
            pf[kc] = U.v;
        }

        // ---- O += P @ V ----
        __builtin_amdgcn_s_setprio(1);
        #pragma unroll
        for (int nb = 0; nb < 4; nb++)
            accO[nb] = __builtin_amdgcn_mfma_f32_32x32x16_bf16(pf[0], vfA[0][nb], accO[nb], 0, 0, 0);
        #pragma unroll
        for (int nb = 0; nb < 4; nb++)
            accO[nb] = __builtin_amdgcn_mfma_f32_32x32x16_bf16(pf[1], vfA[1][nb], accO[nb], 0, 0, 0);
        #pragma unroll
        for (int nb = 0; nb < 4; nb++)
            accO[nb] = __builtin_amdgcn_mfma_f32_32x32x16_bf16(pf[2], vfB[0][nb], accO[nb], 0, 0, 0);
        #pragma unroll
        for (int nb = 0; nb < 4; nb++)
            accO[nb] = __builtin_amdgcn_mfma_f32_32x32x16_bf16(pf[3], vfB[1][nb], accO[nb], 0, 0, 0);
        __builtin_amdgcn_s_setprio(0);
    }

    // ---- dump wave partial (D layout: col=l&31, row=(r&3)+8*(r>>2)+4*hi) ----
    #pragma unroll
    for (int nb = 0; nb < 4; nb++)
        #pragma unroll
        for (int r = 0; r < 16; r++)
            Lacc[w][(r & 3) + 8 * (r >> 2) + hi4][nb * 32 + c31] = accO[nb][r];
    if (l < 32) { Lm[w][c31] = mrow; Ll[w][c31] = lsum; }
    __syncthreads();

    // ---- merge 4 partials: thread t -> row t>>3, cols (t&7)*16 .. +15 ----
    {
        const int row = tid >> 3;
        const int c0  = (tid & 7) * 16;
        float m0 = Lm[0][row], m1 = Lm[1][row], m2 = Lm[2][row], m3 = Lm[3][row];
        float ms = fmaxf(fmaxf(m0, m1), fmaxf(m2, m3));
        float f0 = exp2f(m0 - ms), f1 = exp2f(m1 - ms);
        float f2 = exp2f(m2 - ms), f3 = exp2f(m3 - ms);
        float L = Ll[0][row] * f0 + Ll[1][row] * f1 + Ll[2][row] * f2 + Ll[3][row] * f3;
        float inv = 1.0f / L;
        float* op = &out[((long)b * T_SEQ + q0 + row) * HS + c0];
        #pragma unroll
        for (int j = 0; j < 16; j++) {
            float o = Lacc[0][row][c0 + j] * f0 + Lacc[1][row][c0 + j] * f1
                    + Lacc[2][row][c0 + j] * f2 + Lacc[3][row][c0 + j] * f3;
            op[j] = o * inv;
        }
    }
}

// ---------------- launch ------------------------------------------------------
extern "C" void kernel_launch(void* const* d_in, const int* in_sizes, int n_in,
                              void* d_out, int out_size, void* d_ws, size_t ws_size,
                              hipStream_t stream) {
    const float* x  = (const float*)d_in[0];
    const float* Wk = (const float*)d_in[1];
    const float* Wq = (const float*)d_in[2];
    const float* Wv = (const float*)d_in[3];
    float* out = (float*)d_out;

    char* ws = (char*)d_ws;
    short* Wt  = (short*)ws;                                  // 1.5 MB (swizzled panels)
    short* qg  = (short*)(ws + 1572864);                      // 4 MB
    short* kg  = (short*)(ws + 1572864 + 4194304);            // 4 MB
    short* vtg = (short*)(ws + 1572864 + 8388608);            // 4 MB

    wt_kernel  <<<3072, 256, 0, stream>>>(Wq, Wk, Wv, Wt);
    proj_kernel<<<768,  256, 0, stream>>>(x, Wt, qg, kg, vtg);
    attn_kernel<<<512,  256, 0, stream>>>(qg, kg, vtg, out);
}

// Round 10
// 132.742 us; speedup vs baseline: 2.3067x; 1.2211x over previous
//
#include <hip/hip_runtime.h>
#include <hip/hip_bf16.h>

#define T_SEQ 4096
#define NB 4
#define CEMB 2048
#define HS 128

typedef __attribute__((ext_vector_type(8))) short bf16x8;
typedef __attribute__((ext_vector_type(4))) float f32x4;
typedef __attribute__((ext_vector_type(16))) float f32x16;

__device__ inline short f2bf(float f) {
    union { float f; unsigned u; } v; v.f = f;
    unsigned r = v.u + 0x7FFFu + ((v.u >> 16) & 1u);   // RNE
    return (short)(r >> 16);
}

__device__ inline unsigned pk2(float lo, float hi) {
    unsigned r;
    asm("v_cvt_pk_bf16_f32 %0, %1, %2" : "=v"(r) : "v"(lo), "v"(hi));
    return r;
}

__device__ inline void gld16(const void* gsrc, void* lds) {
    __builtin_amdgcn_global_load_lds(
        (const __attribute__((address_space(1))) unsigned*)gsrc,
        (__attribute__((address_space(3))) unsigned*)lds, 16, 0, 0);
}

// ---------------- kernel 1: W -> pre-swizzled bf16 LDS-image panels ----------
__global__ __launch_bounds__(256) void wt_kernel(
    const float* __restrict__ Wq, const float* __restrict__ Wk,
    const float* __restrict__ Wv, short* __restrict__ Wt) {
    int d = blockIdx.x * 256 + threadIdx.x;     // 3*32*8192 = 786432
    int mat = d >> 18;
    int rm  = d & 262143;
    int s   = rm >> 13;                         // panel 0..31
    int e   = rm & 8191;
    int p   = e * 2;
    int n   = p >> 7;
    int lin = p ^ ((n & 7) << 4);
    int kk  = (lin & 127) >> 1;
    int k   = s * 64 + kk;
    const float* W = (mat == 0) ? Wq : (mat == 1) ? Wk : Wv;
    Wt[d] = f2bf(W[k * HS + n]);
}

// ---------------- kernel 2: q/k/v projection (3-buffer pipeline) -------------
// q pre-scaled by log2(e)/sqrt(2048); k stored as PRE-SWIZZLED 16KB tile
// images (byte ^= (row&7)<<4 within [64][128] tiles) for attn's LDS staging;
// v transposed: bf16 [B][128][T].
__global__ __launch_bounds__(256, 3) void proj_kernel(
    const float* __restrict__ x, const short* __restrict__ Wt,
    short* __restrict__ qg, short* __restrict__ kg, short* __restrict__ vtg) {
    __shared__ short Wlds[3][8192];   // 3 x 16KB panels

    const int tid = threadIdx.x;
    const int w   = tid >> 6;
    const int l   = tid & 63;
    const int lg  = l >> 4;
    const int lr  = l & 15;

    const int bid = blockIdx.x;
    const int wk  = (bid & 7) * 96 + (bid >> 3);   // same-XCD chunking
    const int mat = wk % 3;
    const int m0  = (wk / 3) * 64;

    const short* Wp = Wt + (long)mat * 262144;

    f32x4 acc[8];
    #pragma unroll
    for (int b = 0; b < 8; b++) acc[b] = (f32x4){0.f, 0.f, 0.f, 0.f};

    const float* xrow = x + (long)(m0 + w * 16 + lr) * CEMB;
    const int sw = (lr & 7) << 4;

    float4 xs[3][4];

#define STAGE(S, B) do {                                                   \
        const short* gp_ = Wp + (long)(S) * 8192 + (long)(w * 4) * 512 + l * 8; \
        gld16(gp_,        &Wlds[B][(w * 4 + 0) * 512]);                    \
        gld16(gp_ + 512,  &Wlds[B][(w * 4 + 1) * 512]);                    \
        gld16(gp_ + 1024, &Wlds[B][(w * 4 + 2) * 512]);                    \
        gld16(gp_ + 1536, &Wlds[B][(w * 4 + 3) * 512]);                    \
    } while (0)

#define LOADX(S, B) do {                                                   \
        const float* xn_ = xrow + (S) * 64;                                \
        xs[B][0] = *reinterpret_cast<const float4*>(xn_ + lg * 8);         \
        xs[B][1] = *reinterpret_cast<const float4*>(xn_ + lg * 8 + 4);     \
        xs[B][2] = *reinterpret_cast<const float4*>(xn_ + 32 + lg * 8);    \
        xs[B][3] = *reinterpret_cast<const float4*>(xn_ + 32 + lg * 8 + 4);\
    } while (0)

    STAGE(0, 0);
    LOADX(0, 0);
    STAGE(1, 1);
    LOADX(1, 1);

#define STEP(S, B0, B2) do {                                               \
        asm volatile("s_waitcnt vmcnt(8) lgkmcnt(0)\n\ts_barrier" ::: "memory"); \
        if ((S) + 2 < 32) { STAGE((S) + 2, B2); LOADX((S) + 2, B2); }      \
        bf16x8 a0, a1;                                                     \
        a0[0] = f2bf(xs[B0][0].x); a0[1] = f2bf(xs[B0][0].y);              \
        a0[2] = f2bf(xs[B0][0].z); a0[3] = f2bf(xs[B0][0].w);              \
        a0[4] = f2bf(xs[B0][1].x); a0[5] = f2bf(xs[B0][1].y);              \
        a0[6] = f2bf(xs[B0][1].z); a0[7] = f2bf(xs[B0][1].w);              \
        a1[0] = f2bf(xs[B0][2].x); a1[1] = f2bf(xs[B0][2].y);              \
        a1[2] = f2bf(xs[B0][2].z); a1[3] = f2bf(xs[B0][2].w);              \
        a1[4] = f2bf(xs[B0][3].x); a1[5] = f2bf(xs[B0][3].y);              \
        a1[6] = f2bf(xs[B0][3].z); a1[7] = f2bf(xs[B0][3].w);              \
        const char* lbase_ = (const char*)&Wlds[B0][0];                    \
        _Pragma("unroll")                                                  \
        for (int nt = 0; nt < 8; nt++) {                                   \
            int off_ = (((nt * 16 + lr) * 128 + lg * 16)) ^ sw;            \
            bf16x8 bfr_ = *reinterpret_cast<const bf16x8*>(lbase_ + off_); \
            acc[nt] = __builtin_amdgcn_mfma_f32_16x16x32_bf16(             \
                a0, bfr_, acc[nt], 0, 0, 0);                               \
        }                                                                  \
        _Pragma("unroll")                                                  \
        for (int nt = 0; nt < 8; nt++) {                                   \
            int off_ = (((nt * 16 + lr) * 128 + lg * 16 + 64)) ^ sw;       \
            bf16x8 bfr_ = *reinterpret_cast<const bf16x8*>(lbase_ + off_); \
            acc[nt] = __builtin_amdgcn_mfma_f32_16x16x32_bf16(             \
                a1, bfr_, acc[nt], 0, 0, 0);                               \
        }                                                                  \
    } while (0)

    for (int s = 0; s < 30; s += 3) {
        STEP(s, 0, 2);
        STEP(s + 1, 1, 0);
        STEP(s + 2, 2, 1);
    }
    STEP(30, 0, 2);
    STEP(31, 1, 0);

#undef STEP
#undef LOADX
#undef STAGE

    if (mat == 0) {
        const float scale = 0.0318793851f;  // log2(e) / sqrt(2048), folded into q
        #pragma unroll
        for (int nt = 0; nt < 8; nt++)
            #pragma unroll
            for (int r = 0; r < 4; r++) {
                int row = m0 + w * 16 + lg * 4 + r;
                qg[(long)row * HS + nt * 16 + lr] = f2bf(acc[nt][r] * scale);
            }
    } else if (mat == 1) {
        // K image: tile = m0>>6 (global, = b*64 + tile_in_batch), 8192 shorts/tile,
        // byte offset within tile = (r64*256 + d*2) ^ ((r64&7)<<4)
        short* kt = kg + ((long)(m0 >> 6)) * 8192;
        #pragma unroll
        for (int nt = 0; nt < 8; nt++)
            #pragma unroll
            for (int r = 0; r < 4; r++) {
                int r64  = w * 16 + lg * 4 + r;
                int byte = (r64 * 256 + (nt * 16 + lr) * 2) ^ ((r64 & 7) << 4);
                kt[byte >> 1] = f2bf(acc[nt][r]);
            }
    } else {
        #pragma unroll
        for (int nt = 0; nt < 8; nt++)
            #pragma unroll
            for (int r = 0; r < 4; r++) {
                int row = m0 + w * 16 + lg * 4 + r;
                int b   = row >> 12;
                int tl  = row & 4095;
                vtg[(long)b * (HS * T_SEQ) + (long)(nt * 16 + lr) * T_SEQ + tl]
                    = f2bf(acc[nt][r]);
            }
    }
}

// ---------------- kernel 3: flash attention v4 --------------------------------
// swapped-QK 32x32, KV-split 4 waves/block. K staged into WAVE-PRIVATE LDS
// via global_load_lds from the pre-swizzled kg image (no barriers, no VGPR
// cost); stage of tile t+4 issued right after QK(t), waited with vmcnt(0) at
// next iter top (covered by softmax+PV). V direct-global (VGPR now fits).
// Q hoisted. Merge buffer aliases the K pool (disjoint phases).
__global__ __launch_bounds__(256, 2) void attn_kernel(
    const short* __restrict__ qg, const short* __restrict__ kg,
    const short* __restrict__ vtg, float* __restrict__ out) {
    __shared__ __align__(16) char pool[65536];   // [4 waves][16KB]: K tile, then merge
    __shared__ float Lm[4][32];
    __shared__ float Ll[4][32];

    const int tid = threadIdx.x;
    const int w   = tid >> 6;      // wave = kv-split index
    const int l   = tid & 63;
    const int c31 = l & 31;
    const int hi  = l >> 5;
    const int hi4 = hi << 2;
    const int hi8 = hi << 3;

    const int bid = blockIdx.x;
    const int xcd = bid & 7;
    const int idx = bid >> 3;                        // 0..63
    const int b   = xcd >> 1;                        // batch pinned to XCD pair
    const int qt  = 127 - ((idx << 1) | (xcd & 1));  // 0..127, descending
    const int q0  = qt * 32;
    const int qrow = q0 + c31;                       // this lane's q-row

    const short* kbimg = kg + (long)b * 64 * 8192;   // 64 K-tile images per batch
    const short* vb    = vtg + (long)b * HS * T_SEQ;

    short* Kw = (short*)(pool + (w << 14));          // wave-private 16KB

#define STAGEK(TILE) do {                                                  \
        const short* gp_ = kbimg + (long)(TILE) * 8192 + l * 8;            \
        _Pragma("unroll")                                                  \
        for (int i = 0; i < 16; i++)                                       \
            gld16(gp_ + i * 512, Kw + i * 512 + l * 8);                    \
    } while (0)

    // Q fragments hoisted (col = q-row, k = kc*16 + hi*8 + j)
    bf16x8 qf[8];
    #pragma unroll
    for (int kc = 0; kc < 8; kc++)
        qf[kc] = *reinterpret_cast<const bf16x8*>(
            &qg[(long)(b * T_SEQ + qrow) * HS + kc * 16 + hi8]);

    f32x16 accO[4];
    #pragma unroll
    for (int nb = 0; nb < 4; nb++)
        #pragma unroll
        for (int i = 0; i < 16; i++) accO[nb][i] = 0.f;
    float mrow = -__builtin_inff();
    float lsum = 0.f;

    const int ntk = (qt >> 1) + 1;

    // prologue: stage this wave's first K tile
    STAGEK(w);

    const int swz = (c31 & 7) << 4;
    const int rbA = c31 * 256;
    const int rbB = (32 + c31) * 256;

    #pragma unroll 1
    for (int t = w; t < ntk; t += 4) {
        const int kv0 = t * 64;

        // K-stage for this tile must have landed (issued ~600cy ago in steady state)
        asm volatile("s_waitcnt vmcnt(0)" ::: "memory");

        // ---- issue first half of V early ----
        bf16x8 vfA[2][4];
        #pragma unroll
        for (int kc = 0; kc < 2; kc++)
            #pragma unroll
            for (int nb = 0; nb < 4; nb++)
                vfA[kc][nb] = *reinterpret_cast<const bf16x8*>(
                    &vb[(long)(nb * 32 + c31) * T_SEQ + kv0 + kc * 16 + hi8]);

        // ---- S^T = K @ Q^T, K fragments from swizzled LDS ----
        f32x16 SA, SB;
        #pragma unroll
        for (int i = 0; i < 16; i++) { SA[i] = 0.f; SB[i] = 0.f; }
        __builtin_amdgcn_s_setprio(1);
        #pragma unroll
        for (int kc = 0; kc < 8; kc++) {
            const int cb = kc * 32 + hi * 16;
            bf16x8 ka = *reinterpret_cast<const bf16x8*>(
                (const char*)Kw + ((rbA + cb) ^ swz));
            bf16x8 kb2 = *reinterpret_cast<const bf16x8*>(
                (const char*)Kw + ((rbB + cb) ^ swz));
            SA = __builtin_amdgcn_mfma_f32_32x32x16_bf16(ka,  qf[kc], SA, 0, 0, 0);
            SB = __builtin_amdgcn_mfma_f32_32x32x16_bf16(kb2, qf[kc], SB, 0, 0, 0);
        }
        __builtin_amdgcn_s_setprio(0);

        // ---- stage next K tile (lands during softmax+PV, waited next iter) ----
        if (t + 4 < ntk) STAGEK(t + 4);

        float pA[16], pB[16];
        #pragma unroll
        for (int r = 0; r < 16; r++) { pA[r] = SA[r]; pB[r] = SB[r]; }

        // ---- causal mask (boundary tiles only) ----
        if (kv0 + 63 > q0) {
            #pragma unroll
            for (int r = 0; r < 16; r++) {
                int kr = kv0 + (r & 3) + 8 * (r >> 2) + hi4;
                pA[r] = (kr > qrow)      ? -__builtin_inff() : pA[r];
                pB[r] = (kr + 32 > qrow) ? -__builtin_inff() : pB[r];
            }
        }

        // ---- max tree (in-lane, then 1 cross-shfl) ----
        float t16[16];
        #pragma unroll
        for (int r = 0; r < 16; r++) t16[r] = fmaxf(pA[r], pB[r]);
        #pragma unroll
        for (int s2 = 8; s2 >= 1; s2 >>= 1)
            #pragma unroll
            for (int r = 0; r < 8; r++)
                if (r < s2) t16[r] = fmaxf(t16[r], t16[r + s2]);
        float mt = fmaxf(t16[0], __shfl_xor(t16[0], 32));

        // ---- exact defer-rescale ----
        if (__any(mt > mrow)) {
            float mnew = fmaxf(mrow, mt);
            float fac  = exp2f(mrow - mnew);
            lsum *= fac;
            #pragma unroll
            for (int nb = 0; nb < 4; nb++)
                #pragma unroll
                for (int i = 0; i < 16; i++) accO[nb][i] *= fac;
            mrow = mnew;
        }

        // ---- issue second half of V ----
        bf16x8 vfB[2][4];
        #pragma unroll
        for (int kc = 0; kc < 2; kc++)
            #pragma unroll
            for (int nb = 0; nb < 4; nb++)
                vfB[kc][nb] = *reinterpret_cast<const bf16x8*>(
                    &vb[(long)(nb * 32 + c31) * T_SEQ + kv0 + (kc + 2) * 16 + hi8]);

        // ---- P = exp2(S - m) ----
        #pragma unroll
        for (int r = 0; r < 16; r++) {
            pA[r] = exp2f(pA[r] - mrow);
            pB[r] = exp2f(pB[r] - mrow);
        }
        float s16[16];
        #pragma unroll
        for (int r = 0; r < 16; r++) s16[r] = pA[r] + pB[r];
        #pragma unroll
        for (int s2 = 8; s2 >= 1; s2 >>= 1)
            #pragma unroll
            for (int r = 0; r < 8; r++)
                if (r < s2) s16[r] += s16[r + s2];
        lsum += s16[0] + __shfl_xor(s16[0], 32);

        // ---- pack P into PV A-frags (cvt_pk + lane^32 exchange) ----
        bf16x8 pf[4];
        #pragma unroll
        for (int kc = 0; kc < 4; kc++) {
            const int V0 = 2 * kc, V1 = 2 * kc + 1;
            const int r0 = ((V0 >> 2) << 4) | ((V0 & 3) << 2);
            const int r1 = ((V1 >> 2) << 4) | ((V1 & 3) << 2);
#define PSEL(i) ((i) < 16 ? pA[(i) & 15] : pB[(i) & 15])
            unsigned a0 = pk2(PSEL(r0 + 0), PSEL(r0 + 1));
            unsigned a1 = pk2(PSEL(r0 + 2), PSEL(r0 + 3));
            unsigned b0 = pk2(PSEL(r1 + 0), PSEL(r1 + 1));
            unsigned b1 = pk2(PSEL(r1 + 2), PSEL(r1 + 3));
#undef PSEL
            unsigned k0 = hi ? b0 : a0, k1 = hi ? b1 : a1;
            unsigned s0 = hi ? a0 : b0, s1 = hi ? a1 : b1;
            unsigned g0 = (unsigned)__shfl_xor((int)s0, 32);
            unsigned g1 = (unsigned)__shfl_xor((int)s1, 32);
            union { unsigned u[4]; bf16x8 v; } U;
            U.u[0] = hi ? g0 : k0;
            U.u[1] = hi ? g1 : k1;
            U.u[2] = hi ? k0 : g0;
            U.u[3] = hi ? k1 : g1;
            pf[kc] = U.v;
        }

        // ---- O += P @ V ----
        __builtin_amdgcn_s_setprio(1);
        #pragma unroll
        for (int nb = 0; nb < 4; nb++)
            accO[nb] = __builtin_amdgcn_mfma_f32_32x32x16_bf16(pf[0], vfA[0][nb], accO[nb], 0, 0, 0);
        #pragma unroll
        for (int nb = 0; nb < 4; nb++)
            accO[nb] = __builtin_amdgcn_mfma_f32_32x32x16_bf16(pf[1], vfA[1][nb], accO[nb], 0, 0, 0);
        #pragma unroll
        for (int nb = 0; nb < 4; nb++)
            accO[nb] = __builtin_amdgcn_mfma_f32_32x32x16_bf16(pf[2], vfB[0][nb], accO[nb], 0, 0, 0);
        #pragma unroll
        for (int nb = 0; nb < 4; nb++)
            accO[nb] = __builtin_amdgcn_mfma_f32_32x32x16_bf16(pf[3], vfB[1][nb], accO[nb], 0, 0, 0);
        __builtin_amdgcn_s_setprio(0);
    }
#undef STAGEK

    // ---- dump wave partial into own pool slice (K dead; wave-private alias) ----
    {
        float* LaccW = (float*)(pool + (w << 14));   // [32][128]
        #pragma unroll
        for (int nb = 0; nb < 4; nb++)
            #pragma unroll
            for (int r = 0; r < 16; r++)
                LaccW[((r & 3) + 8 * (r >> 2) + hi4) * 128 + nb * 32 + c31] = accO[nb][r];
        if (l < 32) { Lm[w][c31] = mrow; Ll[w][c31] = lsum; }
    }
    __syncthreads();

    // ---- merge 4 partials: thread t -> row t>>3, cols (t&7)*16 .. +15 ----
    {
        const int row = tid >> 3;
        const int c0  = (tid & 7) * 16;
        float m0 = Lm[0][row], m1 = Lm[1][row], m2 = Lm[2][row], m3 = Lm[3][row];
        float ms = fmaxf(fmaxf(m0, m1), fmaxf(m2, m3));
        float f0 = exp2f(m0 - ms), f1 = exp2f(m1 - ms);
        float f2 = exp2f(m2 - ms), f3 = exp2f(m3 - ms);
        float L = Ll[0][row] * f0 + Ll[1][row] * f1 + Ll[2][row] * f2 + Ll[3][row] * f3;
        float inv = 1.0f / L;
        float* op = &out[((long)b * T_SEQ + q0 + row) * HS + c0];
        const float* L0 = (const float*)(pool);
        const float* L1 = (const float*)(pool + 16384);
        const float* L2 = (const float*)(pool + 32768);
        const float* L3 = (const float*)(pool + 49152);
        #pragma unroll
        for (int j = 0; j < 16; j++) {
            float o = L0[row * 128 + c0 + j] * f0 + L1[row * 128 + c0 + j] * f1
                    + L2[row * 128 + c0 + j] * f2 + L3[row * 128 + c0 + j] * f3;
            op[j] = o * inv;
        }
    }
}

// ---------------- launch ------------------------------------------------------
extern "C" void kernel_launch(void* const* d_in, const int* in_sizes, int n_in,
                              void* d_out, int out_size, void* d_ws, size_t ws_size,
                              hipStream_t stream) {
    const float* x  = (const float*)d_in[0];
    const float* Wk = (const float*)d_in[1];
    const float* Wq = (const float*)d_in[2];
    const float* Wv = (const float*)d_in[3];
    float* out = (float*)d_out;

    char* ws = (char*)d_ws;
    short* Wt  = (short*)ws;                                  // 1.5 MB (swizzled panels)
    short* qg  = (short*)(ws + 1572864);                      // 4 MB
    short* kg  = (short*)(ws + 1572864 + 4194304);            // 4 MB (K tile images)
    short* vtg = (short*)(ws + 1572864 + 8388608);            // 4 MB

    wt_kernel  <<<3072, 256, 0, stream>>>(Wq, Wk, Wv, Wt);
    proj_kernel<<<768,  256, 0, stream>>>(x, Wt, qg, kg, vtg);
    attn_kernel<<<512,  256, 0, stream>>>(qg, kg, vtg, out);
}